// Round 1
// baseline (1872.653 us; speedup 1.0000x reference)
//
#include <hip/hip_runtime.h>
#include <stdint.h>

#define EMAX 320   // max neighbors stored per row (mean ~102, sigma ~10; 320 is >20 sigma)

typedef short bf16x8 __attribute__((ext_vector_type(8)));
typedef float f32x4 __attribute__((ext_vector_type(4)));

__device__ __forceinline__ uint16_t f2bf(float f) {
    union { float f; uint32_t u; } v; v.f = f;
    uint32_t u = v.u;
    uint32_t r = (u + 0x7FFFu + ((u >> 16) & 1u)) >> 16;   // RNE
    return (uint16_t)r;
}
__device__ __forceinline__ float bf2f(uint16_t h) {
    union { uint32_t u; float f; } v; v.u = ((uint32_t)h) << 16;
    return v.f;
}

// ---------------- input conversion ----------------
// X[b*2048+n, 0:768] = concat(req, code) in bf16
__global__ __launch_bounds__(256) void k_convX(const float* __restrict__ req,
                                               const float* __restrict__ code,
                                               uint16_t* __restrict__ X) {
    int r = blockIdx.x;            // 0..16383
    int b = r >> 11, n = r & 2047;
    const float* src = (n < 1024) ? (req  + ((size_t)(b*1024 + n)) * 768)
                                  : (code + ((size_t)(b*1024 + (n-1024))) * 768);
    uint16_t* dst = X + (size_t)r * 768;
    for (int f = threadIdx.x; f < 768; f += 256) dst[f] = f2bf(src[f]);
}

// convert all 5 weight matrices fp32 -> bf16 (layouts preserved: [N,K] row-major = B^T)
__global__ __launch_bounds__(256) void k_convW(const float* wp, const float* wg1, const float* wg2,
                                               const float* wif, const float* wib,
                                               uint16_t* op, uint16_t* og1, uint16_t* og2,
                                               uint16_t* oif, uint16_t* oib) {
    int i = blockIdx.x * 256 + threadIdx.x;       // grid covers 196608
    if (i < 196608) op[i]  = f2bf(wp[i]);
    if (i < 65536)  og1[i] = f2bf(wg1[i]);
    if (i < 32768)  og2[i] = f2bf(wg2[i]);
    if (i < 24576)  { oif[i] = f2bf(wif[i]); oib[i] = f2bf(wib[i]); }
}

// ---------------- edge list build (one wave per adjacency row) ----------------
__global__ __launch_bounds__(256) void k_edges(const float* __restrict__ adj,
                                               uint16_t* __restrict__ eidx,
                                               int* __restrict__ ecnt) {
    int row  = blockIdx.x * 4 + (threadIdx.x >> 6);
    int lane = threadIdx.x & 63;
    const float* arow = adj + (size_t)row * 2048;
    uint16_t* out = eidx + (size_t)row * EMAX;
    int base = 0;
    for (int c = 0; c < 32; ++c) {
        int j = c * 64 + lane;
        float v = arow[j];
        unsigned long long m = __ballot(v > 0.0f);
        if (v > 0.0f) {
            int pos = base + __popcll(m & ((1ull << lane) - 1ull));
            if (pos < EMAX) out[pos] = (uint16_t)j;
        }
        base += __popcll(m);
    }
    if (lane == 0) ecnt[row] = (base < EMAX) ? base : EMAX;
}

// ---------------- bf16 MFMA GEMM: C = act(A[M,K] @ W[N,K]^T + bias) ----------------
// 64x64 tile, BK=64, 4 waves (each wave: 16 rows x 64 cols)
template<int ACT, int OUTBF>
__global__ __launch_bounds__(256) void k_gemm(const uint16_t* __restrict__ A,
                                              const uint16_t* __restrict__ Bw,
                                              const float* __restrict__ bias,
                                              void* __restrict__ Cv,
                                              int M, int N, int K) {
    __shared__ __align__(16) uint16_t As[64 * 64];
    __shared__ __align__(16) uint16_t Bs[64 * 64];
    int tid = threadIdx.x;
    int n0 = blockIdx.x * 64, m0 = blockIdx.y * 64;
    int wave = tid >> 6, lane = tid & 63;
    int quad = lane >> 4, l16 = lane & 15;
    f32x4 acc[4] = {};
    int ar = tid >> 3;            // 0..31
    int ac = (tid & 7) * 8;       // 0..56
    for (int kb = 0; kb < K; kb += 64) {
        *(uint4*)&As[ar * 64 + ac]        = *(const uint4*)(A  + (size_t)(m0 + ar)      * K + kb + ac);
        *(uint4*)&As[(ar + 32) * 64 + ac] = *(const uint4*)(A  + (size_t)(m0 + ar + 32) * K + kb + ac);
        *(uint4*)&Bs[ar * 64 + ac]        = *(const uint4*)(Bw + (size_t)(n0 + ar)      * K + kb + ac);
        *(uint4*)&Bs[(ar + 32) * 64 + ac] = *(const uint4*)(Bw + (size_t)(n0 + ar + 32) * K + kb + ac);
        __syncthreads();
#pragma unroll
        for (int kk = 0; kk < 64; kk += 32) {
            bf16x8 af = *(bf16x8*)&As[(wave * 16 + l16) * 64 + kk + quad * 8];
#pragma unroll
            for (int c = 0; c < 4; ++c) {
                bf16x8 bfr = *(bf16x8*)&Bs[(c * 16 + l16) * 64 + kk + quad * 8];
                acc[c] = __builtin_amdgcn_mfma_f32_16x16x32_bf16(af, bfr, acc[c], 0, 0, 0);
            }
        }
        __syncthreads();
    }
#pragma unroll
    for (int c = 0; c < 4; ++c) {
        int col = n0 + c * 16 + l16;
        float bv = bias ? bias[col] : 0.f;
#pragma unroll
        for (int rg = 0; rg < 4; ++rg) {
            int row = m0 + wave * 16 + quad * 4 + rg;
            float v = acc[c][rg] + bv;
            if (ACT == 1) v = fmaxf(v, 0.f);
            if (OUTBF) ((uint16_t*)Cv)[(size_t)row * N + col] = f2bf(v);
            else       ((float*)Cv)[(size_t)row * N + col] = v;
        }
    }
}

// ---------------- s_src/s_dst = H @ a[:D], H @ a[D:]  (one wave per row) ----------------
__global__ __launch_bounds__(256) void k_attvec(const uint16_t* __restrict__ H,
                                                const float* __restrict__ a,
                                                float* __restrict__ ssrc,
                                                float* __restrict__ sdst, int D) {
    int row  = blockIdx.x * 4 + (threadIdx.x >> 6);
    int lane = threadIdx.x & 63;
    int per = D >> 6;
    const uint16_t* hr = H + (size_t)row * D + lane * per;
    float s0 = 0.f, s1 = 0.f;
    for (int q = 0; q < per; ++q) {
        float hv = bf2f(hr[q]);
        int d = lane * per + q;
        s0 += hv * a[d];
        s1 += hv * a[D + d];
    }
    for (int off = 32; off; off >>= 1) { s0 += __shfl_down(s0, off); s1 += __shfl_down(s1, off); }
    if (lane == 0) { ssrc[row] = s0; sdst[row] = s1; }
}

// ---------------- sparse GAT aggregate: out = epi(softmax_edges @ H) ----------------
template<int D, int LAYER1>
__global__ __launch_bounds__(256) void k_agg(const uint16_t* __restrict__ H,
                                             const float* __restrict__ ssrc,
                                             const float* __restrict__ sdst,
                                             const uint16_t* __restrict__ eidx,
                                             const int* __restrict__ ecnt,
                                             const int* __restrict__ total,
                                             uint16_t* __restrict__ out) {
    __shared__ float eb[EMAX];
    __shared__ uint16_t jb[EMAX];
    __shared__ float red[256];
    int row = blockIdx.x;
    int b = row >> 11, i = row & 2047;
    int tid = threadIdx.x;
    int cnt = ecnt[row];
    float mk = (i < total[b]) ? 1.f : 0.f;
    float acc = 0.f;
    if (cnt > 0) {
        float sv = ssrc[row];
        for (int t = tid; t < cnt; t += 256) {
            int j = eidx[(size_t)row * EMAX + t];
            jb[t] = (uint16_t)j;
            float e = sv + sdst[b * 2048 + j];
            eb[t] = (e > 0.f) ? e : 0.01f * e;     // leaky_relu 0.01
        }
        __syncthreads();
        float lm = -1e30f;
        for (int t = tid; t < cnt; t += 256) lm = fmaxf(lm, eb[t]);
        red[tid] = lm; __syncthreads();
        for (int s = 128; s; s >>= 1) { if (tid < s) red[tid] = fmaxf(red[tid], red[tid + s]); __syncthreads(); }
        float m = red[0]; __syncthreads();
        float ls = 0.f;
        for (int t = tid; t < cnt; t += 256) { float w = __expf(eb[t] - m); eb[t] = w; ls += w; }
        red[tid] = ls; __syncthreads();
        for (int s = 128; s; s >>= 1) { if (tid < s) red[tid] += red[tid + s]; __syncthreads(); }
        float inv = 1.f / red[0];
        if (tid < D) {
            for (int t = 0; t < cnt; ++t)
                acc += eb[t] * bf2f(H[((size_t)(b * 2048 + jb[t])) * D + tid]);
            acc *= inv;
        }
    } else {
        // softmax over all-NEG row is uniform 1/2048 -> mean of H
        if (tid < D) {
            for (int j = 0; j < 2048; ++j) acc += bf2f(H[((size_t)(b * 2048 + j)) * D + tid]);
            acc *= (1.f / 2048.f);
        }
    }
    if (tid < D) {
        float v = LAYER1 ? fmaxf(acc, 0.f) * mk : acc * mk;
        out[(size_t)row * D + tid] = f2bf(v);
    }
}

// ---------------- bidirectional GRU scan: one block per (b,dir), 192 threads ----------------
__global__ __launch_bounds__(192) void k_gru(const float* __restrict__ XPf, const float* __restrict__ XPb,
                                             const float* __restrict__ Whh_f, const float* __restrict__ bhh_f,
                                             const float* __restrict__ Whh_b, const float* __restrict__ bhh_b,
                                             float* __restrict__ GF, float* __restrict__ GB) {
    int dir = blockIdx.x >> 3;
    int b   = blockIdx.x & 7;
    int j   = threadIdx.x;                 // 0..191 (gate-row index)
    const float* XP  = dir ? XPb   : XPf;
    const float* Whh = dir ? Whh_b : Whh_f;
    const float* bhh = dir ? bhh_b : bhh_f;
    float* Y = dir ? GB : GF;
    __shared__ __align__(16) float hbuf[64];
    __shared__ float ghbuf[192];
    __shared__ float xbuf[2][192];
    float4 w[16];
#pragma unroll
    for (int q = 0; q < 16; ++q) w[q] = *(const float4*)&Whh[j * 64 + q * 4];
    float bh = bhh[j];
    if (j < 64) hbuf[j] = 0.f;
    const float4* h4 = (const float4*)hbuf;
    size_t xbase = (size_t)b * 2048 * 192;
    float xcur = XP[xbase + (size_t)(dir ? 2047 : 0) * 192 + j];
    float xnext = 0.f;
    __syncthreads();
    for (int step = 0; step < 2048; ++step) {
        int t = dir ? (2047 - step) : step;
        int p = step & 1;
        xbuf[p][j] = xcur;
        if (step + 1 < 2048) {
            int tn = dir ? (2046 - step) : (step + 1);
            xnext = XP[xbase + (size_t)tn * 192 + j];
        }
        float4 a4 = {0.f, 0.f, 0.f, 0.f};
#pragma unroll
        for (int q = 0; q < 16; ++q) {
            float4 hv = h4[q];
            a4.x += hv.x * w[q].x;
            a4.y += hv.y * w[q].y;
            a4.z += hv.z * w[q].z;
            a4.w += hv.w * w[q].w;
        }
        ghbuf[j] = a4.x + a4.y + a4.z + a4.w + bh;
        __syncthreads();
        if (j < 64) {
            float xr = xbuf[p][j], xz = xbuf[p][64 + j], xn = xbuf[p][128 + j];
            float hr = ghbuf[j], hz = ghbuf[64 + j], hn = ghbuf[128 + j];
            float r = 1.f / (1.f + __expf(-(xr + hr)));
            float z = 1.f / (1.f + __expf(-(xz + hz)));
            float nv = xn + r * hn;
            float n = 2.f / (1.f + __expf(-2.f * nv)) - 1.f;   // tanh
            float hnew = (1.f - z) * n + z * hbuf[j];
            hbuf[j] = hnew;
            Y[((size_t)b * 2048 + t) * 64 + j] = hnew;
        }
        xcur = xnext;
        __syncthreads();
    }
}

// ---------------- masked sum over seq: S[b, 0:128] = sum_{t<total} [gf|gb] ----------------
__global__ __launch_bounds__(256) void k_sred(const float* __restrict__ GF, const float* __restrict__ GB,
                                              const int* __restrict__ total, float* __restrict__ S) {
    int b = blockIdx.x;
    int tid = threadIdx.x;
    int sub = tid >> 7, jj = tid & 127;
    int Tb = total[b];
    float acc = 0.f;
    for (int t = sub; t < Tb; t += 2) {
        const float* src = (jj < 64) ? (GF + ((size_t)b * 2048 + t) * 64 + jj)
                                     : (GB + ((size_t)b * 2048 + t) * 64 + (jj - 64));
        acc += *src;
    }
    __shared__ float red[2][128];
    red[sub][jj] = acc;
    __syncthreads();
    if (tid < 128) S[b * 128 + tid] = red[0][tid] + red[1][tid];
}

// ---------------- classifier head (pooled = b_fus + S/2048 @ Wfus^T) ----------------
__global__ __launch_bounds__(128) void k_final(const float* __restrict__ S,
                                               const float* __restrict__ Wfus, const float* __restrict__ bfus,
                                               const float* __restrict__ Wc1, const float* __restrict__ bc1,
                                               const float* __restrict__ Wc2, const float* __restrict__ bc2,
                                               float* __restrict__ out) {
    __shared__ float pool[64];
    __shared__ float red[128];
    int tid = threadIdx.x;
    for (int b = 0; b < 8; ++b) {
        if (tid < 64) {
            float a = 0.f;
            for (int jj = 0; jj < 128; ++jj) a += S[b * 128 + jj] * Wfus[tid * 128 + jj];
            pool[tid] = bfus[tid] + a * (1.f / 2048.f);
        }
        __syncthreads();
        float a1 = 0.f;
        for (int d = 0; d < 64; ++d) a1 += pool[d] * Wc1[tid * 64 + d];
        float h = fmaxf(a1 + bc1[tid], 0.f);
        red[tid] = h * Wc2[tid];
        __syncthreads();
        for (int s = 64; s; s >>= 1) { if (tid < s) red[tid] += red[tid + s]; __syncthreads(); }
        if (tid == 0) out[b] = 1.f / (1.f + __expf(-(red[0] + bc2[0])));
        __syncthreads();
    }
}

// ---------------- host launch ----------------
extern "C" void kernel_launch(void* const* d_in, const int* in_sizes, int n_in,
                              void* d_out, int out_size, void* d_ws, size_t ws_size,
                              hipStream_t stream) {
    (void)in_sizes; (void)n_in; (void)out_size; (void)ws_size;
    const float* req   = (const float*)d_in[0];
    const float* code  = (const float*)d_in[1];
    const float* adj   = (const float*)d_in[2];
    const int*   total = (const int*)  d_in[3];
    const float* W_proj = (const float*)d_in[4];
    const float* b_proj = (const float*)d_in[5];
    const float* W_g1   = (const float*)d_in[6];
    const float* b_g1   = (const float*)d_in[7];
    const float* a_g1   = (const float*)d_in[8];
    const float* W_g2   = (const float*)d_in[9];
    const float* b_g2   = (const float*)d_in[10];
    const float* a_g2   = (const float*)d_in[11];
    const float* Wih_f  = (const float*)d_in[12];
    const float* Whh_f  = (const float*)d_in[13];
    const float* bih_f  = (const float*)d_in[14];
    const float* bhh_f  = (const float*)d_in[15];
    const float* Wih_b  = (const float*)d_in[16];
    const float* Whh_b  = (const float*)d_in[17];
    const float* bih_b  = (const float*)d_in[18];
    const float* bhh_b  = (const float*)d_in[19];
    const float* W_fus  = (const float*)d_in[20];
    const float* b_fus  = (const float*)d_in[21];
    const float* W_c1   = (const float*)d_in[22];
    const float* b_c1   = (const float*)d_in[23];
    const float* W_c2   = (const float*)d_in[24];
    const float* b_c2   = (const float*)d_in[25];

    char* ws = (char*)d_ws;
    // region R0: X bf16 (25.17 MB), later reused for XPf/XPb fp32 (12.58 MB each)
    uint16_t* Xbf  = (uint16_t*)(ws + 0);
    float*    XPf  = (float*)(ws + 0);
    float*    XPb  = (float*)(ws + 12582912);
    // weights bf16
    uint16_t* WPb  = (uint16_t*)(ws + 25165824);
    uint16_t* WG1b = (uint16_t*)(ws + 25559040);
    uint16_t* WG2b = (uint16_t*)(ws + 25690112);
    uint16_t* WIFb = (uint16_t*)(ws + 25755648);
    uint16_t* WIBb = (uint16_t*)(ws + 25804800);
    // region R2: proj bf16 (8.39 MB), later GF/GB fp32 (4.19 MB each)
    uint16_t* Pbf  = (uint16_t*)(ws + 25853952);
    float*    GF   = (float*)(ws + 25853952);
    float*    GB   = (float*)(ws + 30048256);
    // region R3: H1 bf16 (8.39 MB), later H2 (4.19) + G2 (4.19)
    uint16_t* H1bf = (uint16_t*)(ws + 34242560);
    uint16_t* H2bf = (uint16_t*)(ws + 34242560);
    uint16_t* G2bf = (uint16_t*)(ws + 38436864);
    // region R4: G1 bf16 (8.39 MB)
    uint16_t* G1bf = (uint16_t*)(ws + 42631168);
    // edges
    uint16_t* EIDX = (uint16_t*)(ws + 51019776);
    int*      ECNT = (int*)     (ws + 61505536);
    // attention scalars
    float* s1src = (float*)(ws + 61571072);
    float* s1dst = (float*)(ws + 61636608);
    float* s2src = (float*)(ws + 61702144);
    float* s2dst = (float*)(ws + 61767680);
    float* Sbuf  = (float*)(ws + 61833216);

    // 1. conversions + edge build
    k_convX<<<16384, 256, 0, stream>>>(req, code, Xbf);
    k_convW<<<768, 256, 0, stream>>>(W_proj, W_g1, W_g2, Wih_f, Wih_b, WPb, WG1b, WG2b, WIFb, WIBb);
    k_edges<<<4096, 256, 0, stream>>>(adj, EIDX, ECNT);

    // 2. proj = relu(X @ W_proj^T + b)  [16384,256] bf16
    k_gemm<1, 1><<<dim3(4, 256), 256, 0, stream>>>(Xbf, WPb, b_proj, Pbf, 16384, 256, 768);

    // 3. GAT layer 1
    k_gemm<0, 1><<<dim3(4, 256), 256, 0, stream>>>(Pbf, WG1b, b_g1, H1bf, 16384, 256, 256);
    k_attvec<<<4096, 256, 0, stream>>>(H1bf, a_g1, s1src, s1dst, 256);
    k_agg<256, 1><<<16384, 256, 0, stream>>>(H1bf, s1src, s1dst, EIDX, ECNT, total, G1bf);

    // 4. GAT layer 2
    k_gemm<0, 1><<<dim3(2, 256), 256, 0, stream>>>(G1bf, WG2b, b_g2, H2bf, 16384, 128, 256);
    k_attvec<<<4096, 256, 0, stream>>>(H2bf, a_g2, s2src, s2dst, 128);
    k_agg<128, 0><<<16384, 256, 0, stream>>>(H2bf, s2src, s2dst, EIDX, ECNT, total, G2bf);

    // 5. GRU input projections (fp32 out)
    k_gemm<0, 0><<<dim3(3, 256), 256, 0, stream>>>(G2bf, WIFb, bih_f, XPf, 16384, 192, 128);
    k_gemm<0, 0><<<dim3(3, 256), 256, 0, stream>>>(G2bf, WIBb, bih_b, XPb, 16384, 192, 128);

    // 6. bidirectional GRU scan
    k_gru<<<16, 192, 0, stream>>>(XPf, XPb, Whh_f, bhh_f, Whh_b, bhh_b, GF, GB);

    // 7. masked pool + classifier
    k_sred<<<8, 256, 0, stream>>>(GF, GB, total, Sbuf);
    k_final<<<1, 128, 0, stream>>>(Sbuf, W_fus, b_fus, W_c1, b_c1, W_c2, b_c2, (float*)d_out);
}

// Round 2
// 1594.340 us; speedup vs baseline: 1.1746x; 1.1746x over previous
//
#include <hip/hip_runtime.h>
#include <stdint.h>

#define EMAX 320   // max neighbors stored per row (mean ~102, sigma ~10; 320 is >20 sigma)

typedef short bf16x8 __attribute__((ext_vector_type(8)));
typedef float f32x4 __attribute__((ext_vector_type(4)));

__device__ __forceinline__ uint16_t f2bf(float f) {
    union { float f; uint32_t u; } v; v.f = f;
    uint32_t u = v.u;
    uint32_t r = (u + 0x7FFFu + ((u >> 16) & 1u)) >> 16;   // RNE
    return (uint16_t)r;
}
__device__ __forceinline__ float bf2f(uint16_t h) {
    union { uint32_t u; float f; } v; v.u = ((uint32_t)h) << 16;
    return v.f;
}

// ---------------- input conversion ----------------
__global__ __launch_bounds__(256) void k_convX(const float* __restrict__ req,
                                               const float* __restrict__ code,
                                               uint16_t* __restrict__ X) {
    int r = blockIdx.x;            // 0..16383
    int b = r >> 11, n = r & 2047;
    const float* src = (n < 1024) ? (req  + ((size_t)(b*1024 + n)) * 768)
                                  : (code + ((size_t)(b*1024 + (n-1024))) * 768);
    uint16_t* dst = X + (size_t)r * 768;
    for (int f = threadIdx.x; f < 768; f += 256) dst[f] = f2bf(src[f]);
}

__global__ __launch_bounds__(256) void k_convW(const float* wp, const float* wg1, const float* wg2,
                                               const float* wif, const float* wib,
                                               uint16_t* op, uint16_t* og1, uint16_t* og2,
                                               uint16_t* oif, uint16_t* oib) {
    int i = blockIdx.x * 256 + threadIdx.x;       // grid covers 196608
    if (i < 196608) op[i]  = f2bf(wp[i]);
    if (i < 65536)  og1[i] = f2bf(wg1[i]);
    if (i < 32768)  og2[i] = f2bf(wg2[i]);
    if (i < 24576)  { oif[i] = f2bf(wif[i]); oib[i] = f2bf(wib[i]); }
}

// ---------------- edge list build (one wave per adjacency row) ----------------
__global__ __launch_bounds__(256) void k_edges(const float* __restrict__ adj,
                                               uint16_t* __restrict__ eidx,
                                               int* __restrict__ ecnt) {
    int row  = blockIdx.x * 4 + (threadIdx.x >> 6);
    int lane = threadIdx.x & 63;
    const float* arow = adj + (size_t)row * 2048;
    uint16_t* out = eidx + (size_t)row * EMAX;
    int base = 0;
    for (int c = 0; c < 32; ++c) {
        int j = c * 64 + lane;
        float v = arow[j];
        unsigned long long m = __ballot(v > 0.0f);
        if (v > 0.0f) {
            int pos = base + __popcll(m & ((1ull << lane) - 1ull));
            if (pos < EMAX) out[pos] = (uint16_t)j;
        }
        base += __popcll(m);
    }
    if (lane == 0) ecnt[row] = (base < EMAX) ? base : EMAX;
}

// ---------------- bf16 MFMA GEMM: C = act(A[M,K] @ W[N,K]^T + bias) ----------------
template<int ACT, int OUTBF>
__global__ __launch_bounds__(256) void k_gemm(const uint16_t* __restrict__ A,
                                              const uint16_t* __restrict__ Bw,
                                              const float* __restrict__ bias,
                                              void* __restrict__ Cv,
                                              int M, int N, int K) {
    __shared__ __align__(16) uint16_t As[64 * 64];
    __shared__ __align__(16) uint16_t Bs[64 * 64];
    int tid = threadIdx.x;
    int n0 = blockIdx.x * 64, m0 = blockIdx.y * 64;
    int wave = tid >> 6, lane = tid & 63;
    int quad = lane >> 4, l16 = lane & 15;
    f32x4 acc[4] = {};
    int ar = tid >> 3;            // 0..31
    int ac = (tid & 7) * 8;       // 0..56
    for (int kb = 0; kb < K; kb += 64) {
        *(uint4*)&As[ar * 64 + ac]        = *(const uint4*)(A  + (size_t)(m0 + ar)      * K + kb + ac);
        *(uint4*)&As[(ar + 32) * 64 + ac] = *(const uint4*)(A  + (size_t)(m0 + ar + 32) * K + kb + ac);
        *(uint4*)&Bs[ar * 64 + ac]        = *(const uint4*)(Bw + (size_t)(n0 + ar)      * K + kb + ac);
        *(uint4*)&Bs[(ar + 32) * 64 + ac] = *(const uint4*)(Bw + (size_t)(n0 + ar + 32) * K + kb + ac);
        __syncthreads();
#pragma unroll
        for (int kk = 0; kk < 64; kk += 32) {
            bf16x8 af = *(bf16x8*)&As[(wave * 16 + l16) * 64 + kk + quad * 8];
#pragma unroll
            for (int c = 0; c < 4; ++c) {
                bf16x8 bfr = *(bf16x8*)&Bs[(c * 16 + l16) * 64 + kk + quad * 8];
                acc[c] = __builtin_amdgcn_mfma_f32_16x16x32_bf16(af, bfr, acc[c], 0, 0, 0);
            }
        }
        __syncthreads();
    }
#pragma unroll
    for (int c = 0; c < 4; ++c) {
        int col = n0 + c * 16 + l16;
        float bv = bias ? bias[col] : 0.f;
#pragma unroll
        for (int rg = 0; rg < 4; ++rg) {
            int row = m0 + wave * 16 + quad * 4 + rg;
            float v = acc[c][rg] + bv;
            if (ACT == 1) v = fmaxf(v, 0.f);
            if (OUTBF) ((uint16_t*)Cv)[(size_t)row * N + col] = f2bf(v);
            else       ((float*)Cv)[(size_t)row * N + col] = v;
        }
    }
}

// ---------------- s_src/s_dst = H @ a[:D], H @ a[D:]  (one wave per row) ----------------
__global__ __launch_bounds__(256) void k_attvec(const uint16_t* __restrict__ H,
                                                const float* __restrict__ a,
                                                float* __restrict__ ssrc,
                                                float* __restrict__ sdst, int D) {
    int row  = blockIdx.x * 4 + (threadIdx.x >> 6);
    int lane = threadIdx.x & 63;
    int per = D >> 6;
    const uint16_t* hr = H + (size_t)row * D + lane * per;
    float s0 = 0.f, s1 = 0.f;
    for (int q = 0; q < per; ++q) {
        float hv = bf2f(hr[q]);
        int d = lane * per + q;
        s0 += hv * a[d];
        s1 += hv * a[D + d];
    }
    for (int off = 32; off; off >>= 1) { s0 += __shfl_down(s0, off); s1 += __shfl_down(s1, off); }
    if (lane == 0) { ssrc[row] = s0; sdst[row] = s1; }
}

// ---------------- sparse GAT aggregate: out = epi(softmax_edges @ H) ----------------
// threads = 256 = SUB t-subgroups x NC2 column-pair threads; u32 loads (2 bf16/lane)
template<int D, int LAYER1>
__global__ __launch_bounds__(256) void k_agg(const uint16_t* __restrict__ H,
                                             const float* __restrict__ ssrc,
                                             const float* __restrict__ sdst,
                                             const uint16_t* __restrict__ eidx,
                                             const int* __restrict__ ecnt,
                                             const int* __restrict__ total,
                                             uint16_t* __restrict__ out) {
    constexpr int NC2 = D / 2;          // 128 (D=256) or 64 (D=128)
    constexpr int SUB = 256 / NC2;      // 2 or 4
    __shared__ float eb[EMAX];
    __shared__ uint16_t jb[EMAX];
    __shared__ float red[256];
    __shared__ float paccx[256];
    __shared__ float paccy[256];
    int row = blockIdx.x;
    int b = row >> 11, i = row & 2047;
    int tid = threadIdx.x;
    int cp = tid & (NC2 - 1);
    int sub = tid / NC2;
    // masked row -> output is zero regardless; skip all work (block-uniform branch)
    if (i >= total[b]) {
        if (sub == 0) ((uint32_t*)out)[(size_t)row * NC2 + cp] = 0u;
        return;
    }
    int cnt = ecnt[row];
    float ax = 0.f, ay = 0.f;
    const uint32_t* Hb = (const uint32_t*)(H + (size_t)b * 2048 * D);
    if (cnt > 0) {
        float sv = ssrc[row];
        for (int t = tid; t < cnt; t += 256) {
            int j = eidx[(size_t)row * EMAX + t];
            jb[t] = (uint16_t)j;
            float e = sv + sdst[b * 2048 + j];
            eb[t] = (e > 0.f) ? e : 0.01f * e;     // leaky_relu 0.01
        }
        __syncthreads();
        float lm = -1e30f;
        for (int t = tid; t < cnt; t += 256) lm = fmaxf(lm, eb[t]);
        red[tid] = lm; __syncthreads();
        for (int s = 128; s; s >>= 1) { if (tid < s) red[tid] = fmaxf(red[tid], red[tid + s]); __syncthreads(); }
        float m = red[0]; __syncthreads();
        float ls = 0.f;
        for (int t = tid; t < cnt; t += 256) { float w = __expf(eb[t] - m); eb[t] = w; ls += w; }
        red[tid] = ls; __syncthreads();
        for (int s = 128; s; s >>= 1) { if (tid < s) red[tid] += red[tid + s]; __syncthreads(); }
        float inv = 1.f / red[0];
        for (int t = sub; t < cnt; t += SUB) {
            uint32_t hv = Hb[(size_t)jb[t] * NC2 + cp];
            float w = eb[t];
            ax = fmaf(w, bf2f((uint16_t)hv), ax);
            ay = fmaf(w, bf2f((uint16_t)(hv >> 16)), ay);
        }
        ax *= inv; ay *= inv;
    } else {
        // softmax over all-NEG row is uniform 1/2048 -> mean of H
        for (int t = sub; t < 2048; t += SUB) {
            uint32_t hv = Hb[(size_t)t * NC2 + cp];
            ax += bf2f((uint16_t)hv);
            ay += bf2f((uint16_t)(hv >> 16));
        }
        ax *= (1.f / 2048.f); ay *= (1.f / 2048.f);
    }
    paccx[tid] = ax; paccy[tid] = ay;
    __syncthreads();
    if (sub == 0) {
#pragma unroll
        for (int s2 = 1; s2 < SUB; ++s2) { ax += paccx[s2 * NC2 + cp]; ay += paccy[s2 * NC2 + cp]; }
        if (LAYER1) { ax = fmaxf(ax, 0.f); ay = fmaxf(ay, 0.f); }
        uint32_t pk = (uint32_t)f2bf(ax) | ((uint32_t)f2bf(ay) << 16);
        ((uint32_t*)out)[(size_t)row * NC2 + cp] = pk;
    }
}

// ---------------- GRU scan: ONE WAVE per (b,dir), zero barriers ----------------
// Lane j owns gate rows j (r), 64+j (z), 128+j (n); Whh rows in VGPRs.
// h broadcast via 256B LDS buffer (same-address b128 reads = broadcast, conflict-free).
// Pooled masked sum fused in: S[b*128 + dir*64 + j] = sum_{t<total[b]} h_t[j].
__global__ __launch_bounds__(64, 1) void k_gru(const float* __restrict__ XPf, const float* __restrict__ XPb,
                                               const float* __restrict__ Whh_f, const float* __restrict__ bhh_f,
                                               const float* __restrict__ Whh_b, const float* __restrict__ bhh_b,
                                               const int* __restrict__ total,
                                               float* __restrict__ S) {
    int dir = blockIdx.x >> 3;
    int b   = blockIdx.x & 7;
    int j   = threadIdx.x;                 // 0..63
    const float* XP  = dir ? XPb   : XPf;
    const float* Whh = dir ? Whh_b : Whh_f;
    const float* bhh = dir ? bhh_b : bhh_f;
    float4 wr[16], wz[16], wn[16];
#pragma unroll
    for (int q = 0; q < 16; ++q) {
        wr[q] = *(const float4*)&Whh[(      j) * 64 + q * 4];
        wz[q] = *(const float4*)&Whh[( 64 + j) * 64 + q * 4];
        wn[q] = *(const float4*)&Whh[(128 + j) * 64 + q * 4];
    }
    float br = bhh[j], bz = bhh[64 + j], bn = bhh[128 + j];
    __shared__ __align__(16) float hbuf[64];
    hbuf[j] = 0.f;
    asm volatile("s_waitcnt lgkmcnt(0)" ::: "memory");
    float hj = 0.f, sj = 0.f;
    int Tb = total[b];
    const float* xb = XP + (size_t)b * 2048 * 192;
    int t0 = dir ? 2047 : 0;
    float xr = xb[(size_t)t0 * 192 + j];
    float xz = xb[(size_t)t0 * 192 + 64 + j];
    float xn = xb[(size_t)t0 * 192 + 128 + j];
    const float4* h4p = (const float4*)hbuf;
    for (int step = 0; step < 2048; ++step) {
        int t = dir ? (2047 - step) : step;
        float nxr = 0.f, nxz = 0.f, nxn = 0.f;
        if (step + 1 < 2048) {
            int tn = dir ? (2046 - step) : (step + 1);
            const float* xp = xb + (size_t)tn * 192;
            nxr = xp[j]; nxz = xp[64 + j]; nxn = xp[128 + j];
        }
        float ar0 = 0.f, ar1 = 0.f, az0 = 0.f, az1 = 0.f, an0 = 0.f, an1 = 0.f;
#pragma unroll
        for (int q = 0; q < 16; ++q) {
            float4 h = h4p[q];
            ar0 = fmaf(h.x, wr[q].x, ar0); ar1 = fmaf(h.y, wr[q].y, ar1);
            ar0 = fmaf(h.z, wr[q].z, ar0); ar1 = fmaf(h.w, wr[q].w, ar1);
            az0 = fmaf(h.x, wz[q].x, az0); az1 = fmaf(h.y, wz[q].y, az1);
            az0 = fmaf(h.z, wz[q].z, az0); az1 = fmaf(h.w, wz[q].w, az1);
            an0 = fmaf(h.x, wn[q].x, an0); an1 = fmaf(h.y, wn[q].y, an1);
            an0 = fmaf(h.z, wn[q].z, an0); an1 = fmaf(h.w, wn[q].w, an1);
        }
        float ghr = ar0 + ar1 + br;
        float ghz = az0 + az1 + bz;
        float ghn = an0 + an1 + bn;
        float r = 1.f / (1.f + __expf(-(xr + ghr)));
        float z = 1.f / (1.f + __expf(-(xz + ghz)));
        float nv = xn + r * ghn;
        float n = 2.f / (1.f + __expf(-2.f * nv)) - 1.f;   // tanh
        hj = (1.f - z) * n + z * hj;
        if (t < Tb) sj += hj;
        hbuf[j] = hj;
        asm volatile("s_waitcnt lgkmcnt(0)" ::: "memory");   // drain write; per-wave DS order guarantees RAW
        xr = nxr; xz = nxz; xn = nxn;
    }
    S[b * 128 + dir * 64 + j] = sj;
}

// ---------------- classifier head (pooled = b_fus + S/2048 @ Wfus^T) ----------------
__global__ __launch_bounds__(128) void k_final(const float* __restrict__ S,
                                               const float* __restrict__ Wfus, const float* __restrict__ bfus,
                                               const float* __restrict__ Wc1, const float* __restrict__ bc1,
                                               const float* __restrict__ Wc2, const float* __restrict__ bc2,
                                               float* __restrict__ out) {
    __shared__ float pool[64];
    __shared__ float red[128];
    int tid = threadIdx.x;
    for (int b = 0; b < 8; ++b) {
        if (tid < 64) {
            float a = 0.f;
            for (int jj = 0; jj < 128; ++jj) a += S[b * 128 + jj] * Wfus[tid * 128 + jj];
            pool[tid] = bfus[tid] + a * (1.f / 2048.f);
        }
        __syncthreads();
        float a1 = 0.f;
        for (int d = 0; d < 64; ++d) a1 += pool[d] * Wc1[tid * 64 + d];
        float h = fmaxf(a1 + bc1[tid], 0.f);
        red[tid] = h * Wc2[tid];
        __syncthreads();
        for (int s = 64; s; s >>= 1) { if (tid < s) red[tid] += red[tid + s]; __syncthreads(); }
        if (tid == 0) out[b] = 1.f / (1.f + __expf(-(red[0] + bc2[0])));
        __syncthreads();
    }
}

// ---------------- host launch ----------------
extern "C" void kernel_launch(void* const* d_in, const int* in_sizes, int n_in,
                              void* d_out, int out_size, void* d_ws, size_t ws_size,
                              hipStream_t stream) {
    (void)in_sizes; (void)n_in; (void)out_size; (void)ws_size;
    const float* req   = (const float*)d_in[0];
    const float* code  = (const float*)d_in[1];
    const float* adj   = (const float*)d_in[2];
    const int*   total = (const int*)  d_in[3];
    const float* W_proj = (const float*)d_in[4];
    const float* b_proj = (const float*)d_in[5];
    const float* W_g1   = (const float*)d_in[6];
    const float* b_g1   = (const float*)d_in[7];
    const float* a_g1   = (const float*)d_in[8];
    const float* W_g2   = (const float*)d_in[9];
    const float* b_g2   = (const float*)d_in[10];
    const float* a_g2   = (const float*)d_in[11];
    const float* Wih_f  = (const float*)d_in[12];
    const float* Whh_f  = (const float*)d_in[13];
    const float* bih_f  = (const float*)d_in[14];
    const float* bhh_f  = (const float*)d_in[15];
    const float* Wih_b  = (const float*)d_in[16];
    const float* Whh_b  = (const float*)d_in[17];
    const float* bih_b  = (const float*)d_in[18];
    const float* bhh_b  = (const float*)d_in[19];
    const float* W_fus  = (const float*)d_in[20];
    const float* b_fus  = (const float*)d_in[21];
    const float* W_c1   = (const float*)d_in[22];
    const float* b_c1   = (const float*)d_in[23];
    const float* W_c2   = (const float*)d_in[24];
    const float* b_c2   = (const float*)d_in[25];

    char* ws = (char*)d_ws;
    uint16_t* Xbf  = (uint16_t*)(ws + 0);
    float*    XPf  = (float*)(ws + 0);
    float*    XPb  = (float*)(ws + 12582912);
    uint16_t* WPb  = (uint16_t*)(ws + 25165824);
    uint16_t* WG1b = (uint16_t*)(ws + 25559040);
    uint16_t* WG2b = (uint16_t*)(ws + 25690112);
    uint16_t* WIFb = (uint16_t*)(ws + 25755648);
    uint16_t* WIBb = (uint16_t*)(ws + 25804800);
    uint16_t* Pbf  = (uint16_t*)(ws + 25853952);
    uint16_t* H1bf = (uint16_t*)(ws + 34242560);
    uint16_t* H2bf = (uint16_t*)(ws + 34242560);
    uint16_t* G2bf = (uint16_t*)(ws + 38436864);
    uint16_t* G1bf = (uint16_t*)(ws + 42631168);
    uint16_t* EIDX = (uint16_t*)(ws + 51019776);
    int*      ECNT = (int*)     (ws + 61505536);
    float* s1src = (float*)(ws + 61571072);
    float* s1dst = (float*)(ws + 61636608);
    float* s2src = (float*)(ws + 61702144);
    float* s2dst = (float*)(ws + 61767680);
    float* Sbuf  = (float*)(ws + 61833216);

    // 1. conversions + edge build
    k_convX<<<16384, 256, 0, stream>>>(req, code, Xbf);
    k_convW<<<768, 256, 0, stream>>>(W_proj, W_g1, W_g2, Wih_f, Wih_b, WPb, WG1b, WG2b, WIFb, WIBb);
    k_edges<<<4096, 256, 0, stream>>>(adj, EIDX, ECNT);

    // 2. proj = relu(X @ W_proj^T + b)  [16384,256] bf16
    k_gemm<1, 1><<<dim3(4, 256), 256, 0, stream>>>(Xbf, WPb, b_proj, Pbf, 16384, 256, 768);

    // 3. GAT layer 1
    k_gemm<0, 1><<<dim3(4, 256), 256, 0, stream>>>(Pbf, WG1b, b_g1, H1bf, 16384, 256, 256);
    k_attvec<<<4096, 256, 0, stream>>>(H1bf, a_g1, s1src, s1dst, 256);
    k_agg<256, 1><<<16384, 256, 0, stream>>>(H1bf, s1src, s1dst, EIDX, ECNT, total, G1bf);

    // 4. GAT layer 2
    k_gemm<0, 1><<<dim3(2, 256), 256, 0, stream>>>(G1bf, WG2b, b_g2, H2bf, 16384, 128, 256);
    k_attvec<<<4096, 256, 0, stream>>>(H2bf, a_g2, s2src, s2dst, 128);
    k_agg<128, 0><<<16384, 256, 0, stream>>>(H2bf, s2src, s2dst, EIDX, ECNT, total, G2bf);

    // 5. GRU input projections (fp32 out)
    k_gemm<0, 0><<<dim3(3, 256), 256, 0, stream>>>(G2bf, WIFb, bih_f, XPf, 16384, 192, 128);
    k_gemm<0, 0><<<dim3(3, 256), 256, 0, stream>>>(G2bf, WIBb, bih_b, XPb, 16384, 192, 128);

    // 6. bidirectional GRU scan + fused masked pooling sum
    k_gru<<<16, 64, 0, stream>>>(XPf, XPb, Whh_f, bhh_f, Whh_b, bhh_b, total, Sbuf);

    // 7. classifier
    k_final<<<1, 128, 0, stream>>>(Sbuf, W_fus, b_fus, W_c1, b_c1, W_c2, b_c2, (float*)d_out);
}

// Round 3
// 1525.432 us; speedup vs baseline: 1.2276x; 1.0452x over previous
//
#include <hip/hip_runtime.h>
#include <stdint.h>

#define EMAX 320   // max neighbors stored per row (mean ~102, sigma ~10; 320 is >20 sigma)

typedef short bf16x8 __attribute__((ext_vector_type(8)));
typedef float f32x4 __attribute__((ext_vector_type(4)));

__device__ __forceinline__ uint16_t f2bf(float f) {
    union { float f; uint32_t u; } v; v.f = f;
    uint32_t u = v.u;
    uint32_t r = (u + 0x7FFFu + ((u >> 16) & 1u)) >> 16;   // RNE
    return (uint16_t)r;
}
__device__ __forceinline__ float bf2f(uint16_t h) {
    union { uint32_t u; float f; } v; v.u = ((uint32_t)h) << 16;
    return v.f;
}

// ---------------- input conversion (vectorized: float4 in, ushort4 out) ----------------
__global__ __launch_bounds__(192) void k_convX(const float* __restrict__ req,
                                               const float* __restrict__ code,
                                               uint16_t* __restrict__ X) {
    int r = blockIdx.x;            // 0..16383
    int b = r >> 11, n = r & 2047;
    const float4* src4 = (const float4*)((n < 1024) ? (req  + ((size_t)(b*1024 + n)) * 768)
                                                    : (code + ((size_t)(b*1024 + (n-1024))) * 768));
    ushort4* dst4 = (ushort4*)(X + (size_t)r * 768);
    int f = threadIdx.x;           // 192 float4 groups per row
    float4 v = src4[f];
    ushort4 p;
    p.x = f2bf(v.x); p.y = f2bf(v.y); p.z = f2bf(v.z); p.w = f2bf(v.w);
    dst4[f] = p;
}

__global__ __launch_bounds__(256) void k_convW(const float* wp, const float* wg1, const float* wg2,
                                               const float* wif, const float* wib,
                                               uint16_t* op, uint16_t* og1, uint16_t* og2,
                                               uint16_t* oif, uint16_t* oib) {
    int i = blockIdx.x * 256 + threadIdx.x;       // grid covers 196608
    if (i < 196608) op[i]  = f2bf(wp[i]);
    if (i < 65536)  og1[i] = f2bf(wg1[i]);
    if (i < 32768)  og2[i] = f2bf(wg2[i]);
    if (i < 24576)  { oif[i] = f2bf(wif[i]); oib[i] = f2bf(wib[i]); }
}

// ---------------- edge list build (one wave per adjacency row) ----------------
__global__ __launch_bounds__(256) void k_edges(const float* __restrict__ adj,
                                               uint16_t* __restrict__ eidx,
                                               int* __restrict__ ecnt) {
    int row  = blockIdx.x * 4 + (threadIdx.x >> 6);
    int lane = threadIdx.x & 63;
    const float* arow = adj + (size_t)row * 2048;
    uint16_t* out = eidx + (size_t)row * EMAX;
    int base = 0;
    for (int c = 0; c < 32; ++c) {
        int j = c * 64 + lane;
        float v = arow[j];
        unsigned long long m = __ballot(v > 0.0f);
        if (v > 0.0f) {
            int pos = base + __popcll(m & ((1ull << lane) - 1ull));
            if (pos < EMAX) out[pos] = (uint16_t)j;
        }
        base += __popcll(m);
    }
    if (lane == 0) ecnt[row] = (base < EMAX) ? base : EMAX;
}

// ---------------- bf16 MFMA GEMM: C = act(A[M,K] @ W[N,K]^T + bias) ----------------
template<int ACT, int OUTBF>
__global__ __launch_bounds__(256) void k_gemm(const uint16_t* __restrict__ A,
                                              const uint16_t* __restrict__ Bw,
                                              const float* __restrict__ bias,
                                              void* __restrict__ Cv,
                                              int M, int N, int K) {
    __shared__ __align__(16) uint16_t As[64 * 64];
    __shared__ __align__(16) uint16_t Bs[64 * 64];
    int tid = threadIdx.x;
    int n0 = blockIdx.x * 64, m0 = blockIdx.y * 64;
    int wave = tid >> 6, lane = tid & 63;
    int quad = lane >> 4, l16 = lane & 15;
    f32x4 acc[4] = {};
    int ar = tid >> 3;            // 0..31
    int ac = (tid & 7) * 8;       // 0..56
    for (int kb = 0; kb < K; kb += 64) {
        *(uint4*)&As[ar * 64 + ac]        = *(const uint4*)(A  + (size_t)(m0 + ar)      * K + kb + ac);
        *(uint4*)&As[(ar + 32) * 64 + ac] = *(const uint4*)(A  + (size_t)(m0 + ar + 32) * K + kb + ac);
        *(uint4*)&Bs[ar * 64 + ac]        = *(const uint4*)(Bw + (size_t)(n0 + ar)      * K + kb + ac);
        *(uint4*)&Bs[(ar + 32) * 64 + ac] = *(const uint4*)(Bw + (size_t)(n0 + ar + 32) * K + kb + ac);
        __syncthreads();
#pragma unroll
        for (int kk = 0; kk < 64; kk += 32) {
            bf16x8 af = *(bf16x8*)&As[(wave * 16 + l16) * 64 + kk + quad * 8];
#pragma unroll
            for (int c = 0; c < 4; ++c) {
                bf16x8 bfr = *(bf16x8*)&Bs[(c * 16 + l16) * 64 + kk + quad * 8];
                acc[c] = __builtin_amdgcn_mfma_f32_16x16x32_bf16(af, bfr, acc[c], 0, 0, 0);
            }
        }
        __syncthreads();
    }
#pragma unroll
    for (int c = 0; c < 4; ++c) {
        int col = n0 + c * 16 + l16;
        float bv = bias ? bias[col] : 0.f;
#pragma unroll
        for (int rg = 0; rg < 4; ++rg) {
            int row = m0 + wave * 16 + quad * 4 + rg;
            float v = acc[c][rg] + bv;
            if (ACT == 1) v = fmaxf(v, 0.f);
            if (OUTBF) ((uint16_t*)Cv)[(size_t)row * N + col] = f2bf(v);
            else       ((float*)Cv)[(size_t)row * N + col] = v;
        }
    }
}

// ---------------- s_src/s_dst = H @ a[:D], H @ a[D:]  (one wave per row) ----------------
__global__ __launch_bounds__(256) void k_attvec(const uint16_t* __restrict__ H,
                                                const float* __restrict__ a,
                                                float* __restrict__ ssrc,
                                                float* __restrict__ sdst, int D) {
    int row  = blockIdx.x * 4 + (threadIdx.x >> 6);
    int lane = threadIdx.x & 63;
    int per = D >> 6;
    const uint16_t* hr = H + (size_t)row * D + lane * per;
    float s0 = 0.f, s1 = 0.f;
    for (int q = 0; q < per; ++q) {
        float hv = bf2f(hr[q]);
        int d = lane * per + q;
        s0 += hv * a[d];
        s1 += hv * a[D + d];
    }
    for (int off = 32; off; off >>= 1) { s0 += __shfl_down(s0, off); s1 += __shfl_down(s1, off); }
    if (lane == 0) { ssrc[row] = s0; sdst[row] = s1; }
}

// ---------------- sparse GAT aggregate: out = epi(softmax_edges @ H) ----------------
template<int D, int LAYER1>
__global__ __launch_bounds__(256) void k_agg(const uint16_t* __restrict__ H,
                                             const float* __restrict__ ssrc,
                                             const float* __restrict__ sdst,
                                             const uint16_t* __restrict__ eidx,
                                             const int* __restrict__ ecnt,
                                             const int* __restrict__ total,
                                             uint16_t* __restrict__ out) {
    constexpr int NC2 = D / 2;          // 128 (D=256) or 64 (D=128)
    constexpr int SUB = 256 / NC2;      // 2 or 4
    __shared__ float eb[EMAX];
    __shared__ uint16_t jb[EMAX];
    __shared__ float red[256];
    __shared__ float paccx[256];
    __shared__ float paccy[256];
    int row = blockIdx.x;
    int b = row >> 11, i = row & 2047;
    int tid = threadIdx.x;
    int cp = tid & (NC2 - 1);
    int sub = tid / NC2;
    if (i >= total[b]) {
        if (sub == 0) ((uint32_t*)out)[(size_t)row * NC2 + cp] = 0u;
        return;
    }
    int cnt = ecnt[row];
    float ax = 0.f, ay = 0.f;
    const uint32_t* Hb = (const uint32_t*)(H + (size_t)b * 2048 * D);
    if (cnt > 0) {
        float sv = ssrc[row];
        for (int t = tid; t < cnt; t += 256) {
            int j = eidx[(size_t)row * EMAX + t];
            jb[t] = (uint16_t)j;
            float e = sv + sdst[b * 2048 + j];
            eb[t] = (e > 0.f) ? e : 0.01f * e;     // leaky_relu 0.01
        }
        __syncthreads();
        float lm = -1e30f;
        for (int t = tid; t < cnt; t += 256) lm = fmaxf(lm, eb[t]);
        red[tid] = lm; __syncthreads();
        for (int s = 128; s; s >>= 1) { if (tid < s) red[tid] = fmaxf(red[tid], red[tid + s]); __syncthreads(); }
        float m = red[0]; __syncthreads();
        float ls = 0.f;
        for (int t = tid; t < cnt; t += 256) { float w = __expf(eb[t] - m); eb[t] = w; ls += w; }
        red[tid] = ls; __syncthreads();
        for (int s = 128; s; s >>= 1) { if (tid < s) red[tid] += red[tid + s]; __syncthreads(); }
        float inv = 1.f / red[0];
        for (int t = sub; t < cnt; t += SUB) {
            uint32_t hv = Hb[(size_t)jb[t] * NC2 + cp];
            float w = eb[t];
            ax = fmaf(w, bf2f((uint16_t)hv), ax);
            ay = fmaf(w, bf2f((uint16_t)(hv >> 16)), ay);
        }
        ax *= inv; ay *= inv;
    } else {
        for (int t = sub; t < 2048; t += SUB) {
            uint32_t hv = Hb[(size_t)t * NC2 + cp];
            ax += bf2f((uint16_t)hv);
            ay += bf2f((uint16_t)(hv >> 16));
        }
        ax *= (1.f / 2048.f); ay *= (1.f / 2048.f);
    }
    paccx[tid] = ax; paccy[tid] = ay;
    __syncthreads();
    if (sub == 0) {
#pragma unroll
        for (int s2 = 1; s2 < SUB; ++s2) { ax += paccx[s2 * NC2 + cp]; ay += paccy[s2 * NC2 + cp]; }
        if (LAYER1) { ax = fmaxf(ax, 0.f); ay = fmaxf(ay, 0.f); }
        uint32_t pk = (uint32_t)f2bf(ax) | ((uint32_t)f2bf(ay) << 16);
        ((uint32_t*)out)[(size_t)row * NC2 + cp] = pk;
    }
}

// ---------------- GRU scan: one wave per (b,dir), weights VGPR-resident ----------------
// amdgpu_waves_per_eu(1,1): occupancy pinned at 1 wave/EU so the allocator has no
// incentive to shrink arch-VGPR use -> 192 weight floats stay register-resident.
// x prefetched 4 steps ahead (12 loads in flight, covers ~2000 cyc of HBM latency).
// Paired-accumulator FMA layout targets v_pk_fma_f32 SLP formation.
__global__ __attribute__((amdgpu_flat_work_group_size(64, 64), amdgpu_waves_per_eu(1, 1)))
void k_gru(const float* __restrict__ XPf, const float* __restrict__ XPb,
           const float* __restrict__ Whh_f, const float* __restrict__ bhh_f,
           const float* __restrict__ Whh_b, const float* __restrict__ bhh_b,
           const int* __restrict__ total,
           float* __restrict__ S) {
    int dir = blockIdx.x >> 3;
    int b   = blockIdx.x & 7;
    int j   = threadIdx.x;                 // 0..63
    const float* XP  = dir ? XPb   : XPf;
    const float* Whh = dir ? Whh_b : Whh_f;
    const float* bhh = dir ? bhh_b : bhh_f;
    float4 wr[16], wz[16], wn[16];
#pragma unroll
    for (int q = 0; q < 16; ++q) {
        wr[q] = *(const float4*)&Whh[(      j) * 64 + q * 4];
        wz[q] = *(const float4*)&Whh[( 64 + j) * 64 + q * 4];
        wn[q] = *(const float4*)&Whh[(128 + j) * 64 + q * 4];
    }
    float br = bhh[j], bz = bhh[64 + j], bn = bhh[128 + j];
    __shared__ __align__(16) float hbuf[64];
    hbuf[j] = 0.f;
    float hj = 0.f, sj = 0.f;
    int Tb = total[b];
    const float* xb = XP + (size_t)b * 2048 * 192;
    // 4-deep x prefetch ring
    float pxr[4], pxz[4], pxn[4];
#pragma unroll
    for (int d = 0; d < 4; ++d) {
        int t = dir ? (2047 - d) : d;
        const float* xp = xb + (size_t)t * 192;
        pxr[d] = xp[j]; pxz[d] = xp[64 + j]; pxn[d] = xp[128 + j];
    }
    asm volatile("s_waitcnt lgkmcnt(0)" ::: "memory");   // hbuf init visible before first read
    const float4* h4p = (const float4*)hbuf;
    for (int su = 0; su < 2048; su += 4) {
#pragma unroll
        for (int ph = 0; ph < 4; ++ph) {
            int step = su + ph;
            int t = dir ? (2047 - step) : step;
            float xr = pxr[ph], xz = pxz[ph], xn = pxn[ph];
            // prefetch step+4 (clamped; tail values loaded but never consumed)
            {
                int sp = step + 4;
                int tn = dir ? (2047 - sp) : sp;
                tn = (tn < 0) ? 0 : ((tn > 2047) ? 2047 : tn);
                const float* xp = xb + (size_t)tn * 192;
                pxr[ph] = xp[j]; pxz[ph] = xp[64 + j]; pxn[ph] = xp[128 + j];
            }
            float arx = 0.f, ary = 0.f, azx = 0.f, azy = 0.f, anx = 0.f, any2 = 0.f;
#pragma unroll
            for (int q = 0; q < 16; ++q) {
                float4 h = h4p[q];
                arx = fmaf(h.x, wr[q].x, arx); ary = fmaf(h.y, wr[q].y, ary);
                azx = fmaf(h.x, wz[q].x, azx); azy = fmaf(h.y, wz[q].y, azy);
                anx = fmaf(h.x, wn[q].x, anx); any2 = fmaf(h.y, wn[q].y, any2);
                arx = fmaf(h.z, wr[q].z, arx); ary = fmaf(h.w, wr[q].w, ary);
                azx = fmaf(h.z, wz[q].z, azx); azy = fmaf(h.w, wz[q].w, azy);
                anx = fmaf(h.z, wn[q].z, anx); any2 = fmaf(h.w, wn[q].w, any2);
            }
            float ghr = arx + ary + br;
            float ghz = azx + azy + bz;
            float ghn = anx + any2 + bn;
            float er = __expf(-(xr + ghr));
            float r = __builtin_amdgcn_rcpf(1.f + er);
            float ez = __expf(-(xz + ghz));
            float z = __builtin_amdgcn_rcpf(1.f + ez);
            float nv = fmaf(r, ghn, xn);
            float en = __expf(-2.f * nv);
            float n = fmaf(-2.f, __builtin_amdgcn_rcpf(1.f + en), 1.f);   // tanh(nv)
            hj = fmaf(z, hj - n, n);     // (1-z)*n + z*h
            sj += (t < Tb) ? hj : 0.f;
            hbuf[j] = hj;
            // same-wave DS ops execute in order: next phase's reads see this write.
            asm volatile("" ::: "memory");   // compiler-only ordering fence (no HW stall)
        }
    }
    S[b * 128 + dir * 64 + j] = sj;
}

// ---------------- classifier head (pooled = b_fus + S/2048 @ Wfus^T) ----------------
__global__ __launch_bounds__(128) void k_final(const float* __restrict__ S,
                                               const float* __restrict__ Wfus, const float* __restrict__ bfus,
                                               const float* __restrict__ Wc1, const float* __restrict__ bc1,
                                               const float* __restrict__ Wc2, const float* __restrict__ bc2,
                                               float* __restrict__ out) {
    __shared__ float pool[64];
    __shared__ float red[128];
    int tid = threadIdx.x;
    for (int b = 0; b < 8; ++b) {
        if (tid < 64) {
            float a = 0.f;
            for (int jj = 0; jj < 128; ++jj) a += S[b * 128 + jj] * Wfus[tid * 128 + jj];
            pool[tid] = bfus[tid] + a * (1.f / 2048.f);
        }
        __syncthreads();
        float a1 = 0.f;
        for (int d = 0; d < 64; ++d) a1 += pool[d] * Wc1[tid * 64 + d];
        float h = fmaxf(a1 + bc1[tid], 0.f);
        red[tid] = h * Wc2[tid];
        __syncthreads();
        for (int s = 64; s; s >>= 1) { if (tid < s) red[tid] += red[tid + s]; __syncthreads(); }
        if (tid == 0) out[b] = 1.f / (1.f + __expf(-(red[0] + bc2[0])));
        __syncthreads();
    }
}

// ---------------- host launch ----------------
extern "C" void kernel_launch(void* const* d_in, const int* in_sizes, int n_in,
                              void* d_out, int out_size, void* d_ws, size_t ws_size,
                              hipStream_t stream) {
    (void)in_sizes; (void)n_in; (void)out_size; (void)ws_size;
    const float* req   = (const float*)d_in[0];
    const float* code  = (const float*)d_in[1];
    const float* adj   = (const float*)d_in[2];
    const int*   total = (const int*)  d_in[3];
    const float* W_proj = (const float*)d_in[4];
    const float* b_proj = (const float*)d_in[5];
    const float* W_g1   = (const float*)d_in[6];
    const float* b_g1   = (const float*)d_in[7];
    const float* a_g1   = (const float*)d_in[8];
    const float* W_g2   = (const float*)d_in[9];
    const float* b_g2   = (const float*)d_in[10];
    const float* a_g2   = (const float*)d_in[11];
    const float* Wih_f  = (const float*)d_in[12];
    const float* Whh_f  = (const float*)d_in[13];
    const float* bih_f  = (const float*)d_in[14];
    const float* bhh_f  = (const float*)d_in[15];
    const float* Wih_b  = (const float*)d_in[16];
    const float* Whh_b  = (const float*)d_in[17];
    const float* bih_b  = (const float*)d_in[18];
    const float* bhh_b  = (const float*)d_in[19];
    const float* W_fus  = (const float*)d_in[20];
    const float* b_fus  = (const float*)d_in[21];
    const float* W_c1   = (const float*)d_in[22];
    const float* b_c1   = (const float*)d_in[23];
    const float* W_c2   = (const float*)d_in[24];
    const float* b_c2   = (const float*)d_in[25];

    char* ws = (char*)d_ws;
    uint16_t* Xbf  = (uint16_t*)(ws + 0);
    float*    XPf  = (float*)(ws + 0);
    float*    XPb  = (float*)(ws + 12582912);
    uint16_t* WPb  = (uint16_t*)(ws + 25165824);
    uint16_t* WG1b = (uint16_t*)(ws + 25559040);
    uint16_t* WG2b = (uint16_t*)(ws + 25690112);
    uint16_t* WIFb = (uint16_t*)(ws + 25755648);
    uint16_t* WIBb = (uint16_t*)(ws + 25804800);
    uint16_t* Pbf  = (uint16_t*)(ws + 25853952);
    uint16_t* H1bf = (uint16_t*)(ws + 34242560);
    uint16_t* H2bf = (uint16_t*)(ws + 34242560);
    uint16_t* G2bf = (uint16_t*)(ws + 38436864);
    uint16_t* G1bf = (uint16_t*)(ws + 42631168);
    uint16_t* EIDX = (uint16_t*)(ws + 51019776);
    int*      ECNT = (int*)     (ws + 61505536);
    float* s1src = (float*)(ws + 61571072);
    float* s1dst = (float*)(ws + 61636608);
    float* s2src = (float*)(ws + 61702144);
    float* s2dst = (float*)(ws + 61767680);
    float* Sbuf  = (float*)(ws + 61833216);

    // 1. conversions + edge build
    k_convX<<<16384, 192, 0, stream>>>(req, code, Xbf);
    k_convW<<<768, 256, 0, stream>>>(W_proj, W_g1, W_g2, Wih_f, Wih_b, WPb, WG1b, WG2b, WIFb, WIBb);
    k_edges<<<4096, 256, 0, stream>>>(adj, EIDX, ECNT);

    // 2. proj = relu(X @ W_proj^T + b)  [16384,256] bf16
    k_gemm<1, 1><<<dim3(4, 256), 256, 0, stream>>>(Xbf, WPb, b_proj, Pbf, 16384, 256, 768);

    // 3. GAT layer 1
    k_gemm<0, 1><<<dim3(4, 256), 256, 0, stream>>>(Pbf, WG1b, b_g1, H1bf, 16384, 256, 256);
    k_attvec<<<4096, 256, 0, stream>>>(H1bf, a_g1, s1src, s1dst, 256);
    k_agg<256, 1><<<16384, 256, 0, stream>>>(H1bf, s1src, s1dst, EIDX, ECNT, total, G1bf);

    // 4. GAT layer 2
    k_gemm<0, 1><<<dim3(2, 256), 256, 0, stream>>>(G1bf, WG2b, b_g2, H2bf, 16384, 128, 256);
    k_attvec<<<4096, 256, 0, stream>>>(H2bf, a_g2, s2src, s2dst, 128);
    k_agg<128, 0><<<16384, 256, 0, stream>>>(H2bf, s2src, s2dst, EIDX, ECNT, total, G2bf);

    // 5. GRU input projections (fp32 out)
    k_gemm<0, 0><<<dim3(3, 256), 256, 0, stream>>>(G2bf, WIFb, bih_f, XPf, 16384, 192, 128);
    k_gemm<0, 0><<<dim3(3, 256), 256, 0, stream>>>(G2bf, WIBb, bih_b, XPb, 16384, 192, 128);

    // 6. bidirectional GRU scan + fused masked pooling sum
    k_gru<<<16, 64, 0, stream>>>(XPf, XPb, Whh_f, bhh_f, Whh_b, bhh_b, total, Sbuf);

    // 7. classifier
    k_final<<<1, 128, 0, stream>>>(Sbuf, W_fus, b_fus, W_c1, b_c1, W_c2, b_c2, (float*)d_out);
}

// Round 4
// 1281.986 us; speedup vs baseline: 1.4607x; 1.1899x over previous
//
#include <hip/hip_runtime.h>
#include <stdint.h>

#define EMAX 320   // max neighbors stored per row (mean ~102, sigma ~10; 320 is >20 sigma)

typedef short bf16x8 __attribute__((ext_vector_type(8)));
typedef float f32x4 __attribute__((ext_vector_type(4)));
typedef _Float16 h2 __attribute__((ext_vector_type(2)));

__device__ __forceinline__ uint16_t f2bf(float f) {
    union { float f; uint32_t u; } v; v.f = f;
    uint32_t u = v.u;
    uint32_t r = (u + 0x7FFFu + ((u >> 16) & 1u)) >> 16;   // RNE
    return (uint16_t)r;
}
__device__ __forceinline__ float bf2f(uint16_t h) {
    union { uint32_t u; float f; } v; v.u = ((uint32_t)h) << 16;
    return v.f;
}
__device__ __forceinline__ h2 u2h(uint32_t u) {
    union { uint32_t u; h2 h; } v; v.u = u;
    return v.h;
}

// ---------------- input conversion (vectorized: float4 in, ushort4 out) ----------------
__global__ __launch_bounds__(192) void k_convX(const float* __restrict__ req,
                                               const float* __restrict__ code,
                                               uint16_t* __restrict__ X) {
    int r = blockIdx.x;            // 0..16383
    int b = r >> 11, n = r & 2047;
    const float4* src4 = (const float4*)((n < 1024) ? (req  + ((size_t)(b*1024 + n)) * 768)
                                                    : (code + ((size_t)(b*1024 + (n-1024))) * 768));
    ushort4* dst4 = (ushort4*)(X + (size_t)r * 768);
    int f = threadIdx.x;           // 192 float4 groups per row
    float4 v = src4[f];
    ushort4 p;
    p.x = f2bf(v.x); p.y = f2bf(v.y); p.z = f2bf(v.z); p.w = f2bf(v.w);
    dst4[f] = p;
}

__global__ __launch_bounds__(256) void k_convW(const float* wp, const float* wg1, const float* wg2,
                                               const float* wif, const float* wib,
                                               const float* whf, const float* whb,
                                               uint16_t* op, uint16_t* og1, uint16_t* og2,
                                               uint16_t* oif, uint16_t* oib,
                                               _Float16* ohf, _Float16* ohb) {
    int i = blockIdx.x * 256 + threadIdx.x;       // grid covers 196608
    if (i < 196608) op[i]  = f2bf(wp[i]);
    if (i < 65536)  og1[i] = f2bf(wg1[i]);
    if (i < 32768)  og2[i] = f2bf(wg2[i]);
    if (i < 24576)  { oif[i] = f2bf(wif[i]); oib[i] = f2bf(wib[i]); }
    if (i < 12288)  { ohf[i] = (_Float16)whf[i]; ohb[i] = (_Float16)whb[i]; }
}

// ---------------- edge list build (one wave per adjacency row) ----------------
__global__ __launch_bounds__(256) void k_edges(const float* __restrict__ adj,
                                               uint16_t* __restrict__ eidx,
                                               int* __restrict__ ecnt) {
    int row  = blockIdx.x * 4 + (threadIdx.x >> 6);
    int lane = threadIdx.x & 63;
    const float* arow = adj + (size_t)row * 2048;
    uint16_t* out = eidx + (size_t)row * EMAX;
    int base = 0;
    for (int c = 0; c < 32; ++c) {
        int j = c * 64 + lane;
        float v = arow[j];
        unsigned long long m = __ballot(v > 0.0f);
        if (v > 0.0f) {
            int pos = base + __popcll(m & ((1ull << lane) - 1ull));
            if (pos < EMAX) out[pos] = (uint16_t)j;
        }
        base += __popcll(m);
    }
    if (lane == 0) ecnt[row] = (base < EMAX) ? base : EMAX;
}

// ---------------- bf16 MFMA GEMM: C = act(A[M,K] @ W[N,K]^T + bias) ----------------
template<int ACT, int OUTBF>
__global__ __launch_bounds__(256) void k_gemm(const uint16_t* __restrict__ A,
                                              const uint16_t* __restrict__ Bw,
                                              const float* __restrict__ bias,
                                              void* __restrict__ Cv,
                                              int M, int N, int K) {
    __shared__ __align__(16) uint16_t As[64 * 64];
    __shared__ __align__(16) uint16_t Bs[64 * 64];
    int tid = threadIdx.x;
    int n0 = blockIdx.x * 64, m0 = blockIdx.y * 64;
    int wave = tid >> 6, lane = tid & 63;
    int quad = lane >> 4, l16 = lane & 15;
    f32x4 acc[4] = {};
    int ar = tid >> 3;            // 0..31
    int ac = (tid & 7) * 8;       // 0..56
    for (int kb = 0; kb < K; kb += 64) {
        *(uint4*)&As[ar * 64 + ac]        = *(const uint4*)(A  + (size_t)(m0 + ar)      * K + kb + ac);
        *(uint4*)&As[(ar + 32) * 64 + ac] = *(const uint4*)(A  + (size_t)(m0 + ar + 32) * K + kb + ac);
        *(uint4*)&Bs[ar * 64 + ac]        = *(const uint4*)(Bw + (size_t)(n0 + ar)      * K + kb + ac);
        *(uint4*)&Bs[(ar + 32) * 64 + ac] = *(const uint4*)(Bw + (size_t)(n0 + ar + 32) * K + kb + ac);
        __syncthreads();
#pragma unroll
        for (int kk = 0; kk < 64; kk += 32) {
            bf16x8 af = *(bf16x8*)&As[(wave * 16 + l16) * 64 + kk + quad * 8];
#pragma unroll
            for (int c = 0; c < 4; ++c) {
                bf16x8 bfr = *(bf16x8*)&Bs[(c * 16 + l16) * 64 + kk + quad * 8];
                acc[c] = __builtin_amdgcn_mfma_f32_16x16x32_bf16(af, bfr, acc[c], 0, 0, 0);
            }
        }
        __syncthreads();
    }
#pragma unroll
    for (int c = 0; c < 4; ++c) {
        int col = n0 + c * 16 + l16;
        float bv = bias ? bias[col] : 0.f;
#pragma unroll
        for (int rg = 0; rg < 4; ++rg) {
            int row = m0 + wave * 16 + quad * 4 + rg;
            float v = acc[c][rg] + bv;
            if (ACT == 1) v = fmaxf(v, 0.f);
            if (OUTBF) ((uint16_t*)Cv)[(size_t)row * N + col] = f2bf(v);
            else       ((float*)Cv)[(size_t)row * N + col] = v;
        }
    }
}

// ---------------- s_src/s_dst = H @ a[:D], H @ a[D:]  (one wave per row) ----------------
__global__ __launch_bounds__(256) void k_attvec(const uint16_t* __restrict__ H,
                                                const float* __restrict__ a,
                                                float* __restrict__ ssrc,
                                                float* __restrict__ sdst, int D) {
    int row  = blockIdx.x * 4 + (threadIdx.x >> 6);
    int lane = threadIdx.x & 63;
    int per = D >> 6;
    const uint16_t* hr = H + (size_t)row * D + lane * per;
    float s0 = 0.f, s1 = 0.f;
    for (int q = 0; q < per; ++q) {
        float hv = bf2f(hr[q]);
        int d = lane * per + q;
        s0 += hv * a[d];
        s1 += hv * a[D + d];
    }
    for (int off = 32; off; off >>= 1) { s0 += __shfl_down(s0, off); s1 += __shfl_down(s1, off); }
    if (lane == 0) { ssrc[row] = s0; sdst[row] = s1; }
}

// ---------------- sparse GAT aggregate: out = epi(softmax_edges @ H) ----------------
template<int D, int LAYER1>
__global__ __launch_bounds__(256) void k_agg(const uint16_t* __restrict__ H,
                                             const float* __restrict__ ssrc,
                                             const float* __restrict__ sdst,
                                             const uint16_t* __restrict__ eidx,
                                             const int* __restrict__ ecnt,
                                             const int* __restrict__ total,
                                             uint16_t* __restrict__ out) {
    constexpr int NC2 = D / 2;          // 128 (D=256) or 64 (D=128)
    constexpr int SUB = 256 / NC2;      // 2 or 4
    __shared__ float eb[EMAX];
    __shared__ uint16_t jb[EMAX];
    __shared__ float red[256];
    __shared__ float paccx[256];
    __shared__ float paccy[256];
    int row = blockIdx.x;
    int b = row >> 11, i = row & 2047;
    int tid = threadIdx.x;
    int cp = tid & (NC2 - 1);
    int sub = tid / NC2;
    if (i >= total[b]) {
        if (sub == 0) ((uint32_t*)out)[(size_t)row * NC2 + cp] = 0u;
        return;
    }
    int cnt = ecnt[row];
    float ax = 0.f, ay = 0.f;
    const uint32_t* Hb = (const uint32_t*)(H + (size_t)b * 2048 * D);
    if (cnt > 0) {
        float sv = ssrc[row];
        for (int t = tid; t < cnt; t += 256) {
            int j = eidx[(size_t)row * EMAX + t];
            jb[t] = (uint16_t)j;
            float e = sv + sdst[b * 2048 + j];
            eb[t] = (e > 0.f) ? e : 0.01f * e;     // leaky_relu 0.01
        }
        __syncthreads();
        float lm = -1e30f;
        for (int t = tid; t < cnt; t += 256) lm = fmaxf(lm, eb[t]);
        red[tid] = lm; __syncthreads();
        for (int s = 128; s; s >>= 1) { if (tid < s) red[tid] = fmaxf(red[tid], red[tid + s]); __syncthreads(); }
        float m = red[0]; __syncthreads();
        float ls = 0.f;
        for (int t = tid; t < cnt; t += 256) { float w = __expf(eb[t] - m); eb[t] = w; ls += w; }
        red[tid] = ls; __syncthreads();
        for (int s = 128; s; s >>= 1) { if (tid < s) red[tid] += red[tid + s]; __syncthreads(); }
        float inv = 1.f / red[0];
        for (int t = sub; t < cnt; t += SUB) {
            uint32_t hv = Hb[(size_t)jb[t] * NC2 + cp];
            float w = eb[t];
            ax = fmaf(w, bf2f((uint16_t)hv), ax);
            ay = fmaf(w, bf2f((uint16_t)(hv >> 16)), ay);
        }
        ax *= inv; ay *= inv;
    } else {
        for (int t = sub; t < 2048; t += SUB) {
            uint32_t hv = Hb[(size_t)t * NC2 + cp];
            ax += bf2f((uint16_t)hv);
            ay += bf2f((uint16_t)(hv >> 16));
        }
        ax *= (1.f / 2048.f); ay *= (1.f / 2048.f);
    }
    paccx[tid] = ax; paccy[tid] = ay;
    __syncthreads();
    if (sub == 0) {
#pragma unroll
        for (int s2 = 1; s2 < SUB; ++s2) { ax += paccx[s2 * NC2 + cp]; ay += paccy[s2 * NC2 + cp]; }
        if (LAYER1) { ax = fmaxf(ax, 0.f); ay = fmaxf(ay, 0.f); }
        uint32_t pk = (uint32_t)f2bf(ax) | ((uint32_t)f2bf(ay) << 16);
        ((uint32_t*)out)[(size_t)row * NC2 + cp] = pk;
    }
}

// ---------------- GRU scan: one wave per (b,dir), f16 dot2 matvec ----------------
// v_dot2_f32_f16: f16x2 products, fp32 accumulate -> 96 packed weight dwords per lane
// (fits arch-VGPR budget; no AGPR spill copies). h exchanged via 64-entry f16 LDS
// buffer: 8 broadcast b128 reads per step, same-wave DS ordering (no barriers).
// x prefetched 2 steps ahead via pointer bump into 4-step-padded XP buffers.
__global__ __attribute__((amdgpu_flat_work_group_size(64, 64), amdgpu_waves_per_eu(1, 1)))
void k_gru(const float* __restrict__ XPf, const float* __restrict__ XPb,
           const _Float16* __restrict__ WhF, const _Float16* __restrict__ WhB,
           const float* __restrict__ bhh_f, const float* __restrict__ bhh_b,
           const int* __restrict__ total,
           float* __restrict__ S) {
    int dir = blockIdx.x >> 3;
    int b   = blockIdx.x & 7;
    int j   = threadIdx.x;                 // 0..63
    const float* XP  = dir ? XPb : XPf;
    const _Float16* Wh = dir ? WhB : WhF;
    const float* bhh = dir ? bhh_b : bhh_f;
    // rows j (r), 64+j (z), 128+j (n); 64 halfs each = 32 h2 per gate
    h2 wr[32], wz[32], wn[32];
    {
        const h2* rr = (const h2*)(Wh + (size_t)(      j) * 64);
        const h2* rz = (const h2*)(Wh + (size_t)( 64 + j) * 64);
        const h2* rn = (const h2*)(Wh + (size_t)(128 + j) * 64);
#pragma unroll
        for (int c = 0; c < 32; ++c) { wr[c] = rr[c]; wz[c] = rz[c]; wn[c] = rn[c]; }
    }
    float br = bhh[j], bz = bhh[64 + j], bn = bhh[128 + j];
    __shared__ __align__(16) _Float16 hbuf[64];
    hbuf[j] = (_Float16)0.f;
    float hj = 0.f, sj = 0.f;
    int Tb = total[b];
    const float* xptr = XP + (size_t)b * 2048 * 192 + (size_t)(dir ? 2047 : 0) * 192 + j;
    int xstride = dir ? -192 : 192;
    float xr0 = xptr[0], xz0 = xptr[64], xn0 = xptr[128]; xptr += xstride;
    float xr1 = xptr[0], xz1 = xptr[64], xn1 = xptr[128]; xptr += xstride;
    int t = dir ? 2047 : 0, dt = dir ? -1 : 1;
    const uint4* hv4 = (const uint4*)hbuf;   // 8 x (8 halfs)
    for (int step = 0; step < 2048; ++step) {
        asm volatile("" ::: "memory");       // keep hbuf write->read program order
        float ar0 = 0.f, ar1 = 0.f, az0 = 0.f, az1 = 0.f, an0 = 0.f, an1 = 0.f;
#pragma unroll
        for (int q = 0; q < 8; ++q) {
            uint4 hq = hv4[q];
            h2 h0 = u2h(hq.x), h1 = u2h(hq.y), hh2 = u2h(hq.z), h3 = u2h(hq.w);
            ar0 = __builtin_amdgcn_fdot2(h0, wr[q*4+0], ar0, false);
            ar1 = __builtin_amdgcn_fdot2(h1, wr[q*4+1], ar1, false);
            az0 = __builtin_amdgcn_fdot2(h0, wz[q*4+0], az0, false);
            az1 = __builtin_amdgcn_fdot2(h1, wz[q*4+1], az1, false);
            an0 = __builtin_amdgcn_fdot2(h0, wn[q*4+0], an0, false);
            an1 = __builtin_amdgcn_fdot2(h1, wn[q*4+1], an1, false);
            ar0 = __builtin_amdgcn_fdot2(hh2, wr[q*4+2], ar0, false);
            ar1 = __builtin_amdgcn_fdot2(h3,  wr[q*4+3], ar1, false);
            az0 = __builtin_amdgcn_fdot2(hh2, wz[q*4+2], az0, false);
            az1 = __builtin_amdgcn_fdot2(h3,  wz[q*4+3], az1, false);
            an0 = __builtin_amdgcn_fdot2(hh2, wn[q*4+2], an0, false);
            an1 = __builtin_amdgcn_fdot2(h3,  wn[q*4+3], an1, false);
        }
        float ghr = ar0 + ar1 + br;
        float ghz = az0 + az1 + bz;
        float ghn = an0 + an1 + bn;
        float er = __expf(-(xr0 + ghr));
        float r = __builtin_amdgcn_rcpf(1.f + er);
        float ez = __expf(-(xz0 + ghz));
        float z = __builtin_amdgcn_rcpf(1.f + ez);
        float nv = fmaf(r, ghn, xn0);
        float en = __expf(-2.f * nv);
        float n = fmaf(-2.f, __builtin_amdgcn_rcpf(1.f + en), 1.f);   // tanh(nv)
        hj = fmaf(z, hj - n, n);     // (1-z)*n + z*h
        sj += (t < Tb) ? hj : 0.f;
        hbuf[j] = (_Float16)hj;
        // rotate x regs; prefetch step+2 (tail reads land in the pad region)
        xr0 = xr1; xz0 = xz1; xn0 = xn1;
        xr1 = xptr[0]; xz1 = xptr[64]; xn1 = xptr[128]; xptr += xstride;
        t += dt;
    }
    S[b * 128 + dir * 64 + j] = sj;
}

// ---------------- classifier head (pooled = b_fus + S/2048 @ Wfus^T) ----------------
__global__ __launch_bounds__(128) void k_final(const float* __restrict__ S,
                                               const float* __restrict__ Wfus, const float* __restrict__ bfus,
                                               const float* __restrict__ Wc1, const float* __restrict__ bc1,
                                               const float* __restrict__ Wc2, const float* __restrict__ bc2,
                                               float* __restrict__ out) {
    __shared__ float pool[64];
    __shared__ float red[128];
    int tid = threadIdx.x;
    for (int b = 0; b < 8; ++b) {
        if (tid < 64) {
            float a = 0.f;
            for (int jj = 0; jj < 128; ++jj) a += S[b * 128 + jj] * Wfus[tid * 128 + jj];
            pool[tid] = bfus[tid] + a * (1.f / 2048.f);
        }
        __syncthreads();
        float a1 = 0.f;
        for (int d = 0; d < 64; ++d) a1 += pool[d] * Wc1[tid * 64 + d];
        float h = fmaxf(a1 + bc1[tid], 0.f);
        red[tid] = h * Wc2[tid];
        __syncthreads();
        for (int s = 64; s; s >>= 1) { if (tid < s) red[tid] += red[tid + s]; __syncthreads(); }
        if (tid == 0) out[b] = 1.f / (1.f + __expf(-(red[0] + bc2[0])));
        __syncthreads();
    }
}

// ---------------- host launch ----------------
extern "C" void kernel_launch(void* const* d_in, const int* in_sizes, int n_in,
                              void* d_out, int out_size, void* d_ws, size_t ws_size,
                              hipStream_t stream) {
    (void)in_sizes; (void)n_in; (void)out_size; (void)ws_size;
    const float* req   = (const float*)d_in[0];
    const float* code  = (const float*)d_in[1];
    const float* adj   = (const float*)d_in[2];
    const int*   total = (const int*)  d_in[3];
    const float* W_proj = (const float*)d_in[4];
    const float* b_proj = (const float*)d_in[5];
    const float* W_g1   = (const float*)d_in[6];
    const float* b_g1   = (const float*)d_in[7];
    const float* a_g1   = (const float*)d_in[8];
    const float* W_g2   = (const float*)d_in[9];
    const float* b_g2   = (const float*)d_in[10];
    const float* a_g2   = (const float*)d_in[11];
    const float* Wih_f  = (const float*)d_in[12];
    const float* Whh_f  = (const float*)d_in[13];
    const float* bih_f  = (const float*)d_in[14];
    const float* bhh_f  = (const float*)d_in[15];
    const float* Wih_b  = (const float*)d_in[16];
    const float* Whh_b  = (const float*)d_in[17];
    const float* bih_b  = (const float*)d_in[18];
    const float* bhh_b  = (const float*)d_in[19];
    const float* W_fus  = (const float*)d_in[20];
    const float* b_fus  = (const float*)d_in[21];
    const float* W_c1   = (const float*)d_in[22];
    const float* b_c1   = (const float*)d_in[23];
    const float* W_c2   = (const float*)d_in[24];
    const float* b_c2   = (const float*)d_in[25];

    char* ws = (char*)d_ws;
    // region A [0, 25,165,824): Xbf (bf16 X, stage 1-2); later XPf/XPb (padded, stage 5-6)
    uint16_t* Xbf  = (uint16_t*)(ws + 0);
    float*    XPf  = (float*)(ws + 3072);                 // core: 12,582,912 B, 3072 B pad each side
    float*    XPb  = (float*)(ws + 12589056 + 3072);      // alloc at 12,589,056; ends 25,178,112
    // weights (bf16) - start 25,214,976 (clear of XPb pad)
    uint16_t* WPb  = (uint16_t*)(ws + 25214976);
    uint16_t* WG1b = (uint16_t*)(ws + 25608192);
    uint16_t* WG2b = (uint16_t*)(ws + 25739264);
    uint16_t* WIFb = (uint16_t*)(ws + 25804800);
    uint16_t* WIBb = (uint16_t*)(ws + 25853952);
    // activations
    uint16_t* Pbf  = (uint16_t*)(ws + 25903104);
    uint16_t* H1bf = (uint16_t*)(ws + 34291712);
    uint16_t* H2bf = (uint16_t*)(ws + 34291712);
    uint16_t* G2bf = (uint16_t*)(ws + 38486016);
    uint16_t* G1bf = (uint16_t*)(ws + 42680320);
    // edges
    uint16_t* EIDX = (uint16_t*)(ws + 51068928);
    int*      ECNT = (int*)     (ws + 61554688);
    // attention scalars + pooled sums + f16 GRU weights
    float* s1src = (float*)(ws + 61620224);
    float* s1dst = (float*)(ws + 61685760);
    float* s2src = (float*)(ws + 61751296);
    float* s2dst = (float*)(ws + 61816832);
    float* Sbuf  = (float*)(ws + 61882368);
    _Float16* WhFh = (_Float16*)(ws + 61886464);
    _Float16* WhBh = (_Float16*)(ws + 61911040);

    // 1. conversions + edge build
    k_convX<<<16384, 192, 0, stream>>>(req, code, Xbf);
    k_convW<<<768, 256, 0, stream>>>(W_proj, W_g1, W_g2, Wih_f, Wih_b, Whh_f, Whh_b,
                                     WPb, WG1b, WG2b, WIFb, WIBb, WhFh, WhBh);
    k_edges<<<4096, 256, 0, stream>>>(adj, EIDX, ECNT);

    // 2. proj = relu(X @ W_proj^T + b)  [16384,256] bf16
    k_gemm<1, 1><<<dim3(4, 256), 256, 0, stream>>>(Xbf, WPb, b_proj, Pbf, 16384, 256, 768);

    // 3. GAT layer 1
    k_gemm<0, 1><<<dim3(4, 256), 256, 0, stream>>>(Pbf, WG1b, b_g1, H1bf, 16384, 256, 256);
    k_attvec<<<4096, 256, 0, stream>>>(H1bf, a_g1, s1src, s1dst, 256);
    k_agg<256, 1><<<16384, 256, 0, stream>>>(H1bf, s1src, s1dst, EIDX, ECNT, total, G1bf);

    // 4. GAT layer 2
    k_gemm<0, 1><<<dim3(2, 256), 256, 0, stream>>>(G1bf, WG2b, b_g2, H2bf, 16384, 128, 256);
    k_attvec<<<4096, 256, 0, stream>>>(H2bf, a_g2, s2src, s2dst, 128);
    k_agg<128, 0><<<16384, 256, 0, stream>>>(H2bf, s2src, s2dst, EIDX, ECNT, total, G2bf);

    // 5. GRU input projections (fp32 out, into padded XP cores)
    k_gemm<0, 0><<<dim3(3, 256), 256, 0, stream>>>(G2bf, WIFb, bih_f, XPf, 16384, 192, 128);
    k_gemm<0, 0><<<dim3(3, 256), 256, 0, stream>>>(G2bf, WIBb, bih_b, XPb, 16384, 192, 128);

    // 6. bidirectional GRU scan + fused masked pooling sum
    k_gru<<<16, 64, 0, stream>>>(XPf, XPb, WhFh, WhBh, bhh_f, bhh_b, total, Sbuf);

    // 7. classifier
    k_final<<<1, 128, 0, stream>>>(Sbuf, W_fus, b_fus, W_c1, b_c1, W_c2, b_c2, (float*)d_out);
}

// Round 5
// 1278.491 us; speedup vs baseline: 1.4647x; 1.0027x over previous
//
#include <hip/hip_runtime.h>
#include <stdint.h>

#define EMAX 320   // max neighbors stored per row (mean ~102, sigma ~10; 320 is >20 sigma)

typedef short bf16x8 __attribute__((ext_vector_type(8)));
typedef float f32x4 __attribute__((ext_vector_type(4)));

__device__ __forceinline__ uint16_t f2bf(float f) {
    union { float f; uint32_t u; } v; v.f = f;
    uint32_t u = v.u;
    uint32_t r = (u + 0x7FFFu + ((u >> 16) & 1u)) >> 16;   // RNE
    return (uint16_t)r;
}
__device__ __forceinline__ float bf2f(uint16_t h) {
    union { uint32_t u; float f; } v; v.u = ((uint32_t)h) << 16;
    return v.f;
}

// ---------------- fused prep: convX | convW | edge-build (one launch) ----------------
__global__ __launch_bounds__(256) void k_prep(const float* __restrict__ req, const float* __restrict__ code,
                                              uint16_t* __restrict__ X,
                                              const float* wp, const float* wg1, const float* wg2,
                                              const float* wif, const float* wib,
                                              const float* whf, const float* whb,
                                              const float* bihf, const float* bihb,
                                              uint16_t* op, uint16_t* og1, uint16_t* og2,
                                              uint16_t* oifb, _Float16* ohf, _Float16* ohb, float* bihfb,
                                              const float* __restrict__ adj,
                                              uint16_t* __restrict__ eidx, int* __restrict__ ecnt) {
    int blk = blockIdx.x;
    int tid = threadIdx.x;
    if (blk < 16384) {
        // ---- convX: one row per block, 192 float4 groups ----
        int b = blk >> 11, n = blk & 2047;
        if (tid < 192) {
            const float4* src4 = (const float4*)((n < 1024) ? (req  + ((size_t)(b*1024 + n)) * 768)
                                                            : (code + ((size_t)(b*1024 + (n-1024))) * 768));
            ushort4* dst4 = (ushort4*)(X + (size_t)blk * 768);
            float4 v = src4[tid];
            ushort4 p;
            p.x = f2bf(v.x); p.y = f2bf(v.y); p.z = f2bf(v.z); p.w = f2bf(v.w);
            dst4[tid] = p;
        }
    } else if (blk < 16384 + 768) {
        // ---- convW + packing ----
        int i = (blk - 16384) * 256 + tid;
        if (i < 196608) op[i]  = f2bf(wp[i]);
        if (i < 65536)  og1[i] = f2bf(wg1[i]);
        if (i < 32768)  og2[i] = f2bf(wg2[i]);
        if (i < 24576)  { oifb[i] = f2bf(wif[i]); oifb[24576 + i] = f2bf(wib[i]); }
        if (i < 12288)  { ohf[i] = (_Float16)whf[i]; ohb[i] = (_Float16)whb[i]; }
        if (i < 192)    { bihfb[i] = bihf[i]; bihfb[192 + i] = bihb[i]; }
    } else {
        // ---- edge build: one wave per adjacency row ----
        int row  = (blk - 17152) * 4 + (tid >> 6);
        int lane = tid & 63;
        const float* arow = adj + (size_t)row * 2048;
        uint16_t* out = eidx + (size_t)row * EMAX;
        int base = 0;
        for (int c = 0; c < 32; ++c) {
            int j = c * 64 + lane;
            float v = arow[j];
            unsigned long long m = __ballot(v > 0.0f);
            if (v > 0.0f) {
                int pos = base + __popcll(m & ((1ull << lane) - 1ull));
                if (pos < EMAX) out[pos] = (uint16_t)j;
            }
            base += __popcll(m);
        }
        if (lane == 0) ecnt[row] = (base < EMAX) ? base : EMAX;
    }
}

// ---------------- bf16 MFMA GEMM: C = act(A[M,K] @ W[N,K]^T + bias) ----------------
// MODE: 0 = f32 out (stride N), 1 = bf16 out (stride N), 2 = f32 split at col 192 (both stride 192)
template<int ACT, int MODE>
__global__ __launch_bounds__(256) void k_gemm(const uint16_t* __restrict__ A,
                                              const uint16_t* __restrict__ Bw,
                                              const float* __restrict__ bias,
                                              void* __restrict__ Cv, void* __restrict__ Cv2,
                                              int M, int N, int K) {
    __shared__ __align__(16) uint16_t As[64 * 64];
    __shared__ __align__(16) uint16_t Bs[64 * 64];
    int tid = threadIdx.x;
    int n0 = blockIdx.x * 64, m0 = blockIdx.y * 64;
    int wave = tid >> 6, lane = tid & 63;
    int quad = lane >> 4, l16 = lane & 15;
    f32x4 acc[4] = {};
    int ar = tid >> 3;            // 0..31
    int ac = (tid & 7) * 8;       // 0..56
    for (int kb = 0; kb < K; kb += 64) {
        *(uint4*)&As[ar * 64 + ac]        = *(const uint4*)(A  + (size_t)(m0 + ar)      * K + kb + ac);
        *(uint4*)&As[(ar + 32) * 64 + ac] = *(const uint4*)(A  + (size_t)(m0 + ar + 32) * K + kb + ac);
        *(uint4*)&Bs[ar * 64 + ac]        = *(const uint4*)(Bw + (size_t)(n0 + ar)      * K + kb + ac);
        *(uint4*)&Bs[(ar + 32) * 64 + ac] = *(const uint4*)(Bw + (size_t)(n0 + ar + 32) * K + kb + ac);
        __syncthreads();
#pragma unroll
        for (int kk = 0; kk < 64; kk += 32) {
            bf16x8 af = *(bf16x8*)&As[(wave * 16 + l16) * 64 + kk + quad * 8];
#pragma unroll
            for (int c = 0; c < 4; ++c) {
                bf16x8 bfr = *(bf16x8*)&Bs[(c * 16 + l16) * 64 + kk + quad * 8];
                acc[c] = __builtin_amdgcn_mfma_f32_16x16x32_bf16(af, bfr, acc[c], 0, 0, 0);
            }
        }
        __syncthreads();
    }
#pragma unroll
    for (int c = 0; c < 4; ++c) {
        int col = n0 + c * 16 + l16;
        float bv = bias ? bias[col] : 0.f;
#pragma unroll
        for (int rg = 0; rg < 4; ++rg) {
            int row = m0 + wave * 16 + quad * 4 + rg;
            float v = acc[c][rg] + bv;
            if (ACT == 1) v = fmaxf(v, 0.f);
            if (MODE == 1)      ((uint16_t*)Cv)[(size_t)row * N + col] = f2bf(v);
            else if (MODE == 0) ((float*)Cv)[(size_t)row * N + col] = v;
            else {
                if (col < 192) ((float*)Cv)[(size_t)row * 192 + col] = v;
                else           ((float*)Cv2)[(size_t)row * 192 + (col - 192)] = v;
            }
        }
    }
}

// ---------------- s_src/s_dst = H @ a[:D], H @ a[D:]  (one wave per row) ----------------
template<int D>
__global__ __launch_bounds__(256) void k_attvec(const uint16_t* __restrict__ H,
                                                const float* __restrict__ a,
                                                float* __restrict__ ssrc,
                                                float* __restrict__ sdst) {
    int row  = blockIdx.x * 4 + (threadIdx.x >> 6);
    int lane = threadIdx.x & 63;
    constexpr int PER = D >> 6;               // halves per lane (4 or 2)
    const uint32_t* hr = (const uint32_t*)(H + (size_t)row * D + lane * PER);
    float s0 = 0.f, s1 = 0.f;
#pragma unroll
    for (int q = 0; q < PER / 2; ++q) {
        uint32_t hv = hr[q];
        int d = lane * PER + q * 2;
        float h0 = bf2f((uint16_t)hv), h1 = bf2f((uint16_t)(hv >> 16));
        s0 += h0 * a[d] + h1 * a[d + 1];
        s1 += h0 * a[D + d] + h1 * a[D + d + 1];
    }
    for (int off = 32; off; off >>= 1) { s0 += __shfl_down(s0, off); s1 += __shfl_down(s1, off); }
    if (lane == 0) { ssrc[row] = s0; sdst[row] = s1; }
}

// ---------------- sparse GAT aggregate: out = epi(softmax_edges @ H) ----------------
template<int D, int LAYER1>
__global__ __launch_bounds__(256) void k_agg(const uint16_t* __restrict__ H,
                                             const float* __restrict__ ssrc,
                                             const float* __restrict__ sdst,
                                             const uint16_t* __restrict__ eidx,
                                             const int* __restrict__ ecnt,
                                             const int* __restrict__ total,
                                             uint16_t* __restrict__ out) {
    constexpr int NC2 = D / 2;          // 128 (D=256) or 64 (D=128)
    constexpr int SUB = 256 / NC2;      // 2 or 4
    __shared__ float eb[EMAX];
    __shared__ uint16_t jb[EMAX];
    __shared__ float red[256];
    __shared__ float paccx[256];
    __shared__ float paccy[256];
    int row = blockIdx.x;
    int b = row >> 11, i = row & 2047;
    int tid = threadIdx.x;
    int cp = tid & (NC2 - 1);
    int sub = tid / NC2;
    if (i >= total[b]) {
        if (sub == 0) ((uint32_t*)out)[(size_t)row * NC2 + cp] = 0u;
        return;
    }
    int cnt = ecnt[row];
    float ax = 0.f, ay = 0.f;
    const uint32_t* Hb = (const uint32_t*)(H + (size_t)b * 2048 * D);
    if (cnt > 0) {
        float sv = ssrc[row];
        for (int t = tid; t < cnt; t += 256) {
            int j = eidx[(size_t)row * EMAX + t];
            jb[t] = (uint16_t)j;
            float e = sv + sdst[b * 2048 + j];
            eb[t] = (e > 0.f) ? e : 0.01f * e;     // leaky_relu 0.01
        }
        __syncthreads();
        float lm = -1e30f;
        for (int t = tid; t < cnt; t += 256) lm = fmaxf(lm, eb[t]);
        red[tid] = lm; __syncthreads();
        for (int s = 128; s; s >>= 1) { if (tid < s) red[tid] = fmaxf(red[tid], red[tid + s]); __syncthreads(); }
        float m = red[0]; __syncthreads();
        float ls = 0.f;
        for (int t = tid; t < cnt; t += 256) { float w = __expf(eb[t] - m); eb[t] = w; ls += w; }
        red[tid] = ls; __syncthreads();
        for (int s = 128; s; s >>= 1) { if (tid < s) red[tid] += red[tid + s]; __syncthreads(); }
        float inv = 1.f / red[0];
        for (int t = sub; t < cnt; t += SUB) {
            uint32_t hv = Hb[(size_t)jb[t] * NC2 + cp];
            float w = eb[t];
            ax = fmaf(w, bf2f((uint16_t)hv), ax);
            ay = fmaf(w, bf2f((uint16_t)(hv >> 16)), ay);
        }
        ax *= inv; ay *= inv;
    } else {
        for (int t = sub; t < 2048; t += SUB) {
            uint32_t hv = Hb[(size_t)t * NC2 + cp];
            ax += bf2f((uint16_t)hv);
            ay += bf2f((uint16_t)(hv >> 16));
        }
        ax *= (1.f / 2048.f); ay *= (1.f / 2048.f);
    }
    paccx[tid] = ax; paccy[tid] = ay;
    __syncthreads();
    if (sub == 0) {
#pragma unroll
        for (int s2 = 1; s2 < SUB; ++s2) { ax += paccx[s2 * NC2 + cp]; ay += paccy[s2 * NC2 + cp]; }
        if (LAYER1) { ax = fmaxf(ax, 0.f); ay = fmaxf(ay, 0.f); }
        uint32_t pk = (uint32_t)f2bf(ax) | ((uint32_t)f2bf(ay) << 16);
        ((uint32_t*)out)[(size_t)row * NC2 + cp] = pk;
    }
}

// ---------------- GRU scan: one wave per (b,dir), inline-asm v_dot2_f32_f16 ----------------
// "v" constraints pin the 96 packed-f16 weight dwords to ARCH VGPRs (the HIP allocator
// otherwise parks them in AGPRs and pays ~96 v_accvgpr_read per step — measured r4).
#define DOT2(acc, hh, ww) asm("v_dot2_f32_f16 %0, %1, %2, %0" : "+v"(acc) : "v"(hh), "v"(ww))
__global__ __attribute__((amdgpu_flat_work_group_size(64, 64), amdgpu_waves_per_eu(1, 1)))
void k_gru(const float* __restrict__ XPf, const float* __restrict__ XPb,
           const _Float16* __restrict__ WhF, const _Float16* __restrict__ WhB,
           const float* __restrict__ bhh_f, const float* __restrict__ bhh_b,
           const int* __restrict__ total,
           float* __restrict__ S) {
    int dir = blockIdx.x >> 3;
    int b   = blockIdx.x & 7;
    int j   = threadIdx.x;                 // 0..63
    const float* XP  = dir ? XPb : XPf;
    const uint32_t* Wd = (const uint32_t*)(dir ? WhB : WhF);
    const float* bhh = dir ? bhh_b : bhh_f;
    // rows j (r), 64+j (z), 128+j (n); 64 halves = 32 packed dwords per gate row
    uint32_t wr[32], wz[32], wn[32];
#pragma unroll
    for (int c = 0; c < 32; ++c) {
        wr[c] = Wd[(size_t)(      j) * 32 + c];
        wz[c] = Wd[(size_t)( 64 + j) * 32 + c];
        wn[c] = Wd[(size_t)(128 + j) * 32 + c];
    }
    float br = bhh[j], bz = bhh[64 + j], bn = bhh[128 + j];
    __shared__ __align__(16) _Float16 hbuf[64];
    hbuf[j] = (_Float16)0.f;
    float hj = 0.f, sj = 0.f;
    int Tb = total[b];
    const float* xptr = XP + (size_t)b * 2048 * 192 + (size_t)(dir ? 2047 : 0) * 192 + j;
    int xstride = dir ? -192 : 192;
    float xr0 = xptr[0], xz0 = xptr[64], xn0 = xptr[128]; xptr += xstride;
    float xr1 = xptr[0], xz1 = xptr[64], xn1 = xptr[128]; xptr += xstride;
    int t = dir ? 2047 : 0, dt = dir ? -1 : 1;
    const uint4* hv4 = (const uint4*)hbuf;   // 8 x (8 halves)
    for (int step = 0; step < 2048; ++step) {
        asm volatile("" ::: "memory");       // keep hbuf write->read program order
        float ar0 = br, ar1 = 0.f, az0 = bz, az1 = 0.f, an0 = bn, an1 = 0.f;
#pragma unroll
        for (int q = 0; q < 8; ++q) {
            uint4 hq = hv4[q];
            DOT2(ar0, hq.x, wr[q*4+0]); DOT2(ar1, hq.y, wr[q*4+1]);
            DOT2(az0, hq.x, wz[q*4+0]); DOT2(az1, hq.y, wz[q*4+1]);
            DOT2(an0, hq.x, wn[q*4+0]); DOT2(an1, hq.y, wn[q*4+1]);
            DOT2(ar0, hq.z, wr[q*4+2]); DOT2(ar1, hq.w, wr[q*4+3]);
            DOT2(az0, hq.z, wz[q*4+2]); DOT2(az1, hq.w, wz[q*4+3]);
            DOT2(an0, hq.z, wn[q*4+2]); DOT2(an1, hq.w, wn[q*4+3]);
        }
        float ghr = ar0 + ar1;
        float ghz = az0 + az1;
        float ghn = an0 + an1;
        float er = __expf(-(xr0 + ghr));
        float r = __builtin_amdgcn_rcpf(1.f + er);
        float ez = __expf(-(xz0 + ghz));
        float z = __builtin_amdgcn_rcpf(1.f + ez);
        float nv = fmaf(r, ghn, xn0);
        float en = __expf(-2.f * nv);
        float n = fmaf(-2.f, __builtin_amdgcn_rcpf(1.f + en), 1.f);   // tanh(nv)
        hj = fmaf(z, hj - n, n);     // (1-z)*n + z*h
        sj += (t < Tb) ? hj : 0.f;
        hbuf[j] = (_Float16)hj;
        // rotate x regs; prefetch step+2 (tail reads land in the pad region)
        xr0 = xr1; xz0 = xz1; xn0 = xn1;
        xr1 = xptr[0]; xz1 = xptr[64]; xn1 = xptr[128]; xptr += xstride;
        t += dt;
    }
    S[b * 128 + dir * 64 + j] = sj;
}

// ---------------- classifier head (pooled = b_fus + S/2048 @ Wfus^T) ----------------
__global__ __launch_bounds__(128) void k_final(const float* __restrict__ S,
                                               const float* __restrict__ Wfus, const float* __restrict__ bfus,
                                               const float* __restrict__ Wc1, const float* __restrict__ bc1,
                                               const float* __restrict__ Wc2, const float* __restrict__ bc2,
                                               float* __restrict__ out) {
    __shared__ float pool[64];
    __shared__ float red[128];
    int tid = threadIdx.x;
    for (int b = 0; b < 8; ++b) {
        if (tid < 64) {
            float a = 0.f;
            for (int jj = 0; jj < 128; ++jj) a += S[b * 128 + jj] * Wfus[tid * 128 + jj];
            pool[tid] = bfus[tid] + a * (1.f / 2048.f);
        }
        __syncthreads();
        float a1 = 0.f;
        for (int d = 0; d < 64; ++d) a1 += pool[d] * Wc1[tid * 64 + d];
        float h = fmaxf(a1 + bc1[tid], 0.f);
        red[tid] = h * Wc2[tid];
        __syncthreads();
        for (int s = 64; s; s >>= 1) { if (tid < s) red[tid] += red[tid + s]; __syncthreads(); }
        if (tid == 0) out[b] = 1.f / (1.f + __expf(-(red[0] + bc2[0])));
        __syncthreads();
    }
}

// ---------------- host launch ----------------
extern "C" void kernel_launch(void* const* d_in, const int* in_sizes, int n_in,
                              void* d_out, int out_size, void* d_ws, size_t ws_size,
                              hipStream_t stream) {
    (void)in_sizes; (void)n_in; (void)out_size; (void)ws_size;
    const float* req   = (const float*)d_in[0];
    const float* code  = (const float*)d_in[1];
    const float* adj   = (const float*)d_in[2];
    const int*   total = (const int*)  d_in[3];
    const float* W_proj = (const float*)d_in[4];
    const float* b_proj = (const float*)d_in[5];
    const float* W_g1   = (const float*)d_in[6];
    const float* b_g1   = (const float*)d_in[7];
    const float* a_g1   = (const float*)d_in[8];
    const float* W_g2   = (const float*)d_in[9];
    const float* b_g2   = (const float*)d_in[10];
    const float* a_g2   = (const float*)d_in[11];
    const float* Wih_f  = (const float*)d_in[12];
    const float* Whh_f  = (const float*)d_in[13];
    const float* bih_f  = (const float*)d_in[14];
    const float* bhh_f  = (const float*)d_in[15];
    const float* Wih_b  = (const float*)d_in[16];
    const float* Whh_b  = (const float*)d_in[17];
    const float* bih_b  = (const float*)d_in[18];
    const float* bhh_b  = (const float*)d_in[19];
    const float* W_fus  = (const float*)d_in[20];
    const float* b_fus  = (const float*)d_in[21];
    const float* W_c1   = (const float*)d_in[22];
    const float* b_c1   = (const float*)d_in[23];
    const float* W_c2   = (const float*)d_in[24];
    const float* b_c2   = (const float*)d_in[25];

    char* ws = (char*)d_ws;
    // region A: Xbf (bf16 X, stages 1-2); later XPf/XPb fp32, 3072 B pads for prefetch overrun
    uint16_t* Xbf  = (uint16_t*)(ws + 0);
    float*    XPf  = (float*)(ws + 3072);
    float*    XPb  = (float*)(ws + 12589056 + 3072);
    // weights (bf16); WIFB is packed [384,128] (f rows then b rows)
    uint16_t* WPb  = (uint16_t*)(ws + 25214976);
    uint16_t* WG1b = (uint16_t*)(ws + 25608192);
    uint16_t* WG2b = (uint16_t*)(ws + 25739264);
    uint16_t* WIFB = (uint16_t*)(ws + 25804800);
    // activations
    uint16_t* Pbf  = (uint16_t*)(ws + 25903104);
    uint16_t* H1bf = (uint16_t*)(ws + 34291712);
    uint16_t* H2bf = (uint16_t*)(ws + 34291712);
    uint16_t* G2bf = (uint16_t*)(ws + 38486016);
    uint16_t* G1bf = (uint16_t*)(ws + 42680320);
    // edges
    uint16_t* EIDX = (uint16_t*)(ws + 51068928);
    int*      ECNT = (int*)     (ws + 61554688);
    // attention scalars + pooled sums + f16 GRU weights + packed bih
    float* s1src = (float*)(ws + 61620224);
    float* s1dst = (float*)(ws + 61685760);
    float* s2src = (float*)(ws + 61751296);
    float* s2dst = (float*)(ws + 61816832);
    float* Sbuf  = (float*)(ws + 61882368);
    _Float16* WhFh = (_Float16*)(ws + 61886464);
    _Float16* WhBh = (_Float16*)(ws + 61911040);
    float* BIHFB   = (float*)(ws + 61935616);

    // 1. fused prep: convX (16384 blocks) | convW (768) | edges (4096)
    k_prep<<<21248, 256, 0, stream>>>(req, code, Xbf,
                                      W_proj, W_g1, W_g2, Wih_f, Wih_b, Whh_f, Whh_b, bih_f, bih_b,
                                      WPb, WG1b, WG2b, WIFB, WhFh, WhBh, BIHFB,
                                      adj, EIDX, ECNT);

    // 2. proj = relu(X @ W_proj^T + b)  [16384,256] bf16
    k_gemm<1, 1><<<dim3(4, 256), 256, 0, stream>>>(Xbf, WPb, b_proj, Pbf, nullptr, 16384, 256, 768);

    // 3. GAT layer 1
    k_gemm<0, 1><<<dim3(4, 256), 256, 0, stream>>>(Pbf, WG1b, b_g1, H1bf, nullptr, 16384, 256, 256);
    k_attvec<256><<<4096, 256, 0, stream>>>(H1bf, a_g1, s1src, s1dst);
    k_agg<256, 1><<<16384, 256, 0, stream>>>(H1bf, s1src, s1dst, EIDX, ECNT, total, G1bf);

    // 4. GAT layer 2
    k_gemm<0, 1><<<dim3(2, 256), 256, 0, stream>>>(G1bf, WG2b, b_g2, H2bf, nullptr, 16384, 128, 256);
    k_attvec<128><<<4096, 256, 0, stream>>>(H2bf, a_g2, s2src, s2dst);
    k_agg<128, 0><<<16384, 256, 0, stream>>>(H2bf, s2src, s2dst, EIDX, ECNT, total, G2bf);

    // 5. both GRU input projections in one packed GEMM (N=384, split epilogue)
    k_gemm<0, 2><<<dim3(6, 256), 256, 0, stream>>>(G2bf, WIFB, BIHFB, XPf, XPb, 16384, 384, 128);

    // 6. bidirectional GRU scan + fused masked pooling sum
    k_gru<<<16, 64, 0, stream>>>(XPf, XPb, WhFh, WhBh, bhh_f, bhh_b, total, Sbuf);

    // 7. classifier
    k_final<<<1, 128, 0, stream>>>(Sbuf, W_fus, b_fus, W_c1, b_c1, W_c2, b_c2, (float*)d_out);
}